// Round 6
// baseline (893.711 us; speedup 1.0000x reference)
//
#include <hip/hip_runtime.h>
#include <math.h>

// Problem: B=16, L=S=1024, H=8, E=64, d=512, Lf=513 (freq rows PADDED to 514)
// Pipeline: split-transpose(q) -> split-repack(W) -> conv+GLU (MFMA v3,
//           occupancy-tiled) -> rfft(q2) -> transpose(k) -> rfft ->
//           transpose(v) -> rfft -> vf-transpose -> attn(MFMA, L2-direct K/V)
//           -> irfft
// All matmul-shaped compute runs on mfma_f32_16x16x32_bf16 with a 3-product
// error-compensated hi/lo split (~2^-17 per product; below f32-FFT floor).
// conv v3: round-4 loop structure (no hand pipeline -- r5's pipeline spilled,
// WRITE_SIZE +18MB scratch); latency attacked with TLP instead: per-wave
// N-tile 64->32 (acc 4x2, 32 AGPR), grid 1024->2048, launch_bounds(256,3)
// -> 3 blocks/CU instead of 2.
// Workspace: 4 regions x 8,421,376 floats = 134,742,016 bytes.

typedef __attribute__((ext_vector_type(8))) short bf16x8;
typedef __attribute__((ext_vector_type(4))) float f32x4;

union U8 { bf16x8 v; unsigned u[4]; };

__device__ __forceinline__ unsigned short f2b(float x) {  // f32 -> bf16 RNE
  unsigned u = __float_as_uint(x);
  return (unsigned short)((u + 0x7FFFu + ((u >> 16) & 1u)) >> 16);
}
__device__ __forceinline__ float b2f(unsigned short h) {
  return __uint_as_float(((unsigned)h) << 16);
}
__device__ __forceinline__ unsigned cvtpk_bf16(float lo, float hi) {
  unsigned r;  // dst.lo16 = bf16(lo), dst.hi16 = bf16(hi)
  asm("v_cvt_pk_bf16_f32 %0, %1, %2" : "=v"(r) : "v"(lo), "v"(hi));
  return r;
}

// ---------------- Stockham FFT core, N=1024, 256 threads ----------------
__device__ __forceinline__ void fft1024(float2* b0, float2* b1,
                                        const float2* twd, int tid) {
  float2* src = b0;
  float2* dst = b1;
#pragma unroll
  for (int st = 0; st < 10; ++st) {
    __syncthreads();
#pragma unroll
    for (int qq = 0; qq < 2; ++qq) {
      int bi = tid + qq * 256;          // butterfly index in [0,512)
      int m = 1 << st;
      int j = bi >> st;
      int jm = j << st;
      float2 c0 = src[bi];
      float2 c1 = src[bi + 512];
      float2 w = twd[jm];
      float2 sum, dif, tw;
      sum.x = c0.x + c1.x; sum.y = c0.y + c1.y;
      dif.x = c0.x - c1.x; dif.y = c0.y - c1.y;
      tw.x = dif.x * w.x - dif.y * w.y;
      tw.y = dif.x * w.y + dif.y * w.x;
      dst[bi + jm] = sum;
      dst[bi + jm + m] = tw;
    }
    float2* tmp = src; src = dst; dst = tmp;
  }
  __syncthreads();
}

// ---------------- transpose: f32 [B][1024][512] -> f32 [B][512][1024] ---
__global__ __launch_bounds__(256) void transpose_kernel(
    const float* __restrict__ in, float* __restrict__ out) {
  __shared__ float tile[32][33];
  int b = blockIdx.z;
  int s0 = blockIdx.x * 32;
  int c0 = blockIdx.y * 32;
  int tx = threadIdx.x & 31;
  int ty = threadIdx.x >> 5;            // 0..7
  const float* ip = in + (size_t)b * (1024 * 512);
  float* op = out + (size_t)b * (1024 * 512);
#pragma unroll
  for (int i = 0; i < 32; i += 8)
    tile[ty + i][tx] = ip[(size_t)(s0 + ty + i) * 512 + c0 + tx];
  __syncthreads();
#pragma unroll
  for (int i = 0; i < 32; i += 8)
    op[(size_t)(c0 + ty + i) * 1024 + s0 + tx] = tile[tx][ty + i];
}

// ------- q split-transpose: f32 [B][1024 l][512 c] -> bf16-split pair ---
__global__ __launch_bounds__(256) void transpose_q_split(
    const float* __restrict__ in, unsigned* __restrict__ XPhi,
    unsigned* __restrict__ XPlo) {
  __shared__ float tile[32][33];
  int b = blockIdx.z;
  int l0 = blockIdx.x * 32;
  int c0 = blockIdx.y * 32;
  int tx = threadIdx.x & 31;
  int ty = threadIdx.x >> 5;            // 0..7
  const float* ip = in + (size_t)b * (1024 * 512);
#pragma unroll
  for (int i = 0; i < 32; i += 8)
    tile[ty + i][tx] = ip[(size_t)(l0 + ty + i) * 512 + c0 + tx];
  __syncthreads();
  int p = threadIdx.x & 15;
  int lb = threadIdx.x >> 4;            // 0..15
#pragma unroll
  for (int i = 0; i < 2; ++i) {
    int ll = lb + i * 16;
    float v0 = tile[ll][2 * p];
    float v1 = tile[ll][2 * p + 1];
    unsigned short h0 = f2b(v0), h1 = f2b(v1);
    unsigned short q0 = f2b(v0 - b2f(h0)), q1 = f2b(v1 - b2f(h1));
    size_t o = ((size_t)b * 1024 + l0 + ll) * 256 + (c0 >> 1) + p;
    XPhi[o] = (unsigned)h0 | ((unsigned)h1 << 16);
    XPlo[o] = (unsigned)q0 | ((unsigned)q1 << 16);
  }
}

// ------- W split-repack: [1024 og][512 c][3 t] f32 ->
//         Wsp[(p*3+t)*1024 + og] uint2 {hi_pair, lo_pair}, p = c/2 -------
__global__ __launch_bounds__(256) void transpose_w_split(
    const float* __restrict__ Win, uint2* __restrict__ Wsp) {
  __shared__ float tile[32][49];        // [og][48 ct = 8 pairs x 3 t x 2]
  int og0 = blockIdx.x * 32;
  int ct0 = blockIdx.y * 48;
  int tid = threadIdx.x;
#pragma unroll
  for (int i = 0; i < 6; ++i) {
    int flat = tid + i * 256;
    int og = flat / 48, ct = flat % 48;
    tile[og][ct] = Win[(size_t)(og0 + og) * 1536 + ct0 + ct];
  }
  __syncthreads();
  int ogl = tid & 31;
  int s = tid >> 5;                     // 0..7
#pragma unroll
  for (int i = 0; i < 3; ++i) {
    int pt = s + i * 8;                 // 0..23
    int pl = pt / 3, t = pt % 3;
    float v0 = tile[ogl][pl * 6 + t];       // c = 2*(ct0/6 + pl)
    float v1 = tile[ogl][pl * 6 + 3 + t];   // c+1
    unsigned short h0 = f2b(v0), h1 = f2b(v1);
    unsigned short q0 = f2b(v0 - b2f(h0)), q1 = f2b(v1 - b2f(h1));
    Wsp[((size_t)(ct0 / 6 + pl) * 3 + t) * 1024 + og0 + ogl] =
        make_uint2((unsigned)h0 | ((unsigned)h1 << 16),
                   (unsigned)q0 | ((unsigned)q1 << 16));
  }
}

// ------- Conv1d(512->1024,k=3,pad=1) + GLU via MFMA v3 ------------------
// GEMM: C[og][l] = sum_{c,t} W[og][c][t] * X[c][l+t-1]; per block M=64 og,
// N=128 l (4 waves x 32), K=512c x 3t, 3-product hi/lo split.
// Round-4 loop structure; occupancy 3 blocks/CU (acc 4x2 = 32 AGPR).
// Grid 2048 = 16 b x 16 ca x 8 l, XCD-swizzled (each XCD owns 2 batches).
__global__ __launch_bounds__(256, 3) void conv_glu_mfma(
    const unsigned* __restrict__ XPhi, const unsigned* __restrict__ XPlo,
    const uint2* __restrict__ Wsp, const float* __restrict__ bias,
    float* __restrict__ q2t) {
  __shared__ unsigned Whi[3 * 64 * 18];
  __shared__ unsigned Wlo[3 * 64 * 18];

  int tid = threadIdx.x;
  int w = tid >> 6;                     // wave 0..3
  int lane = tid & 63;
  int grp = lane >> 4;                  // k-group 0..3
  int lid = lane & 15;

  unsigned v0 = blockIdx.x;             // 0..2047
  int xcd = (int)(v0 & 7u);
  int j = (int)(v0 >> 3);               // 0..255
  int b = xcd * 2 + (j >> 7);
  int rem = j & 127;
  int ca = (rem >> 3) * 32;             // GLU channel base (16 values)
  int l0 = (rem & 7) * 128;             // l base (8 values)

  const unsigned* xh = XPhi + (size_t)b * 1024 * 256;
  const unsigned* xl = XPlo + (size_t)b * 1024 * 256;

  int lbase = l0 + w * 32 + lid;        // + ni*16 + t - 1 per fragment

  f32x4 acc[4][2];
#pragma unroll
  for (int mi = 0; mi < 4; ++mi)
#pragma unroll
    for (int ni = 0; ni < 2; ++ni) acc[mi][ni] = {0.f, 0.f, 0.f, 0.f};

  for (int c0 = 0; c0 < 512; c0 += 32) {
    __syncthreads();
    // stage W tile: 16 pairs x 3 t x 64 og (a-rows 0..31, g-rows 32..63)
#pragma unroll
    for (int i = 0; i < 12; ++i) {
      int flat = tid + i * 256;
      int ogi = flat & 63;
      int r = flat >> 6;                // 0..47
      int t = r % 3, p = r / 3;
      int og = (ogi < 32) ? (ca + ogi) : (480 + ca + ogi);
      uint2 g = Wsp[((size_t)((c0 >> 1) + p) * 3 + t) * 1024 + og];
      Whi[(t * 64 + ogi) * 18 + p] = g.x;
      Wlo[(t * 64 + ogi) * 18 + p] = g.y;
    }
    __syncthreads();

#pragma unroll
    for (int t = 0; t < 3; ++t) {
      U8 Bh[2], Bl[2];
#pragma unroll
      for (int ni = 0; ni < 2; ++ni) {
        unsigned gl = (unsigned)(lbase + ni * 16 + t - 1);
        uint4 dh = make_uint4(0, 0, 0, 0), dl = make_uint4(0, 0, 0, 0);
        if (gl < 1024u) {
          size_t off = (size_t)gl * 256 + (c0 >> 1) + 4 * grp;
          dh = *(const uint4*)(xh + off);
          dl = *(const uint4*)(xl + off);
        }
        Bh[ni].u[0] = dh.x; Bh[ni].u[1] = dh.y;
        Bh[ni].u[2] = dh.z; Bh[ni].u[3] = dh.w;
        Bl[ni].u[0] = dl.x; Bl[ni].u[1] = dl.y;
        Bl[ni].u[2] = dl.z; Bl[ni].u[3] = dl.w;
      }
#pragma unroll
      for (int mi = 0; mi < 4; ++mi) {
        U8 Ah, Al;
        {
          int base = (t * 64 + mi * 16 + lid) * 18 + 4 * grp;
          uint2 h0 = *(const uint2*)&Whi[base];
          uint2 h1 = *(const uint2*)&Whi[base + 2];
          uint2 g0 = *(const uint2*)&Wlo[base];
          uint2 g1 = *(const uint2*)&Wlo[base + 2];
          Ah.u[0] = h0.x; Ah.u[1] = h0.y; Ah.u[2] = h1.x; Ah.u[3] = h1.y;
          Al.u[0] = g0.x; Al.u[1] = g0.y; Al.u[2] = g1.x; Al.u[3] = g1.y;
        }
#pragma unroll
        for (int ni = 0; ni < 2; ++ni) {
          acc[mi][ni] = __builtin_amdgcn_mfma_f32_16x16x32_bf16(
              Ah.v, Bl[ni].v, acc[mi][ni], 0, 0, 0);
          acc[mi][ni] = __builtin_amdgcn_mfma_f32_16x16x32_bf16(
              Al.v, Bh[ni].v, acc[mi][ni], 0, 0, 0);
          acc[mi][ni] = __builtin_amdgcn_mfma_f32_16x16x32_bf16(
              Ah.v, Bh[ni].v, acc[mi][ni], 0, 0, 0);
        }
      }
    }
  }

  // epilogue: GLU is lane-local (a at mi, g at mi+2, same lane)
#pragma unroll
  for (int mi = 0; mi < 2; ++mi)
#pragma unroll
    for (int rr = 0; rr < 4; ++rr) {
      int row = mi * 16 + grp * 4 + rr;     // 0..31
      float ba = bias[ca + row];
      float bg = bias[512 + ca + row];
      float* orow =
          q2t + ((size_t)b * 512 + ca + row) * 1024 + l0 + w * 32 + lid;
#pragma unroll
      for (int ni = 0; ni < 2; ++ni) {
        float a = acc[mi][ni][rr] + ba;
        float g = acc[mi + 2][ni][rr] + bg;
        orow[ni * 16] = a / (1.f + __expf(-g));
      }
    }
}

// ------- Forward rfft: f32 row [1024] -> 513 bf16-split complex ---------
__global__ __launch_bounds__(256) void fft_fwd_kernel(
    const float* __restrict__ in, ushort4* __restrict__ out, float scale) {
  __shared__ float2 sb0[1024];
  __shared__ float2 sb1[1024];
  __shared__ float2 twd[512];
  int tid = threadIdx.x;
  size_t r = blockIdx.x;                // row = (b*8+h)*64 + e
  const float* ip = in + r * 1024;
#pragma unroll
  for (int i = 0; i < 4; ++i) {
    int idx = tid + i * 256;
    sb0[idx] = make_float2(ip[idx], 0.f);
  }
  for (int kk = tid; kk < 512; kk += 256) {
    float ang = -6.283185307179586f * (float)kk * (1.0f / 1024.0f);
    float sn, cs;
    __sincosf(ang, &sn, &cs);
    twd[kk] = make_float2(cs, sn);
  }
  fft1024(sb0, sb1, twd, tid);
  ushort4* op = out + r * 514;          // padded row stride
  for (int x = tid; x < 513; x += 256) {
    float2 v = sb0[x];
    float re = v.x * scale, im = v.y * scale;
    unsigned short rh = f2b(re), ih = f2b(im);
    unsigned short rl = f2b(re - b2f(rh)), il = f2b(im - b2f(ih));
    op[x] = make_ushort4(rh, ih, rl, il);
  }
  if (tid == 0) op[513] = make_ushort4(0, 0, 0, 0);
}

// ------- vf transpose: [bh][64 e][514 y] uint2 -> vfT [bh][514 y][64 e] --
__global__ __launch_bounds__(256) void vft_kernel(
    const uint2* __restrict__ vf, uint2* __restrict__ vfT) {
  __shared__ uint2 tile[64][65];
  int bh = blockIdx.y;
  int y0 = blockIdx.x * 64;
  int tid = threadIdx.x;
  const uint2* src = vf + (size_t)bh * 64 * 514;
  uint2* dst = vfT + (size_t)bh * 514 * 64;
#pragma unroll
  for (int i = 0; i < 16; ++i) {
    int flat = tid + i * 256;
    int e = flat >> 6, y = flat & 63;
    int gy = y0 + y;
    uint2 d = make_uint2(0, 0);
    if (gy < 514) d = src[(size_t)e * 514 + gy];
    tile[e][y] = d;
  }
  __syncthreads();
#pragma unroll
  for (int i = 0; i < 16; ++i) {
    int flat = tid + i * 256;
    int y = flat >> 6, e = flat & 63;
    int gy = y0 + y;
    if (gy < 514) dst[(size_t)gy * 64 + e] = tile[e][y];
  }
}

// ---------------- Fused frequency attention v3 (MFMA, L2-direct K/V) -----
template <bool TAIL>
__device__ __forceinline__ void attn_tile(
    int y0, const uint2* __restrict__ kb, const uint2* __restrict__ vb,
    const U8 (&Ah)[2][4], const U8 (&Al)[2][4],
    unsigned* Shi, unsigned* Slo, float* zacc, f32x4* ore, f32x4* oim,
    int w, int grp, int lid) {
  int yk = y0 + 16 * w + lid;           // GEMM1 column owned by this lane
  uint2 BK[4][4];
  bool kval = !TAIL || (yk < 514);
#pragma unroll
  for (int ks = 0; ks < 4; ++ks)
#pragma unroll
    for (int jp = 0; jp < 4; ++jp) {
      int e = ks * 16 + grp * 4 + jp;
      if (!TAIL) {
        BK[ks][jp] = kb[(size_t)e * 514 + yk];
      } else {
        uint2 d = make_uint2(0, 0);
        if (kval) d = kb[(size_t)e * 514 + yk];
        BK[ks][jp] = d;
      }
    }
  f32x4 cre[2] = {{0.f, 0.f, 0.f, 0.f}, {0.f, 0.f, 0.f, 0.f}};
  f32x4 cim[2] = {{0.f, 0.f, 0.f, 0.f}, {0.f, 0.f, 0.f, 0.f}};
#pragma unroll
  for (int ks = 0; ks < 4; ++ks) {
    U8 bhh, bll, bih, bil;
#pragma unroll
    for (int jp = 0; jp < 4; ++jp) {
      unsigned uh = BK[ks][jp].x, ul = BK[ks][jp].y;
      bhh.u[jp] = uh;                                  // (kr, ki)
      bll.u[jp] = ul;
      bih.u[jp] = ((uh >> 16) ^ 0x8000u) | (uh << 16); // (-ki, kr)
      bil.u[jp] = ((ul >> 16) ^ 0x8000u) | (ul << 16);
    }
#pragma unroll
    for (int mt = 0; mt < 2; ++mt) {
      cre[mt] = __builtin_amdgcn_mfma_f32_16x16x32_bf16(Ah[mt][ks].v, bhh.v, cre[mt], 0, 0, 0);
      cre[mt] = __builtin_amdgcn_mfma_f32_16x16x32_bf16(Al[mt][ks].v, bhh.v, cre[mt], 0, 0, 0);
      cre[mt] = __builtin_amdgcn_mfma_f32_16x16x32_bf16(Ah[mt][ks].v, bll.v, cre[mt], 0, 0, 0);
      cim[mt] = __builtin_amdgcn_mfma_f32_16x16x32_bf16(Ah[mt][ks].v, bih.v, cim[mt], 0, 0, 0);
      cim[mt] = __builtin_amdgcn_mfma_f32_16x16x32_bf16(Al[mt][ks].v, bih.v, cim[mt], 0, 0, 0);
      cim[mt] = __builtin_amdgcn_mfma_f32_16x16x32_bf16(Ah[mt][ks].v, bil.v, cim[mt], 0, 0, 0);
    }
  }
  // ---- gate + L1 partial + split scores to LDS ----
#pragma unroll
  for (int mt = 0; mt < 2; ++mt)
#pragma unroll
    for (int r = 0; r < 4; ++r) {
      float sre = cre[mt][r], sim = cim[mt][r];
      float m = sqrtf(sre * sre + sim * sim);
      float f = 1.f + 1.f / (1.f + __expf(-m));
      zacc[mt * 4 + r] += m * f;
      float wre = sre * f, wim = sim * f;
      unsigned dh = cvtpk_bf16(wre, wim);
      float rre = wre - __uint_as_float(dh << 16);
      float rim = wim - __uint_as_float(dh & 0xffff0000u);
      unsigned dl = cvtpk_bf16(rre, rim);
      int x = mt * 16 + grp * 4 + r;
      int idx = x * 64 + ((16 * w + lid) ^ ((x & 15) << 2));
      Shi[idx] = dh;
      Slo[idx] = dl;
    }
  __syncthreads();
  // ---- GEMM2: of[x][e] += sc * vf ----
#pragma unroll
  for (int ks = 0; ks < 4; ++ks) {
    uint2 BV[4];
#pragma unroll
    for (int jp = 0; jp < 4; ++jp) {
      int yv = y0 + ks * 16 + grp * 4 + jp;
      if (!TAIL) {
        BV[jp] = vb[(size_t)yv * 64 + 16 * w + lid];
      } else {
        uint2 d = make_uint2(0, 0);
        if (yv < 514) d = vb[(size_t)yv * 64 + 16 * w + lid];
        BV[jp] = d;
      }
    }
    U8 bvh, bvl, bvi, bvj;
#pragma unroll
    for (int jp = 0; jp < 4; ++jp) {
      unsigned uh = BV[jp].x, ul = BV[jp].y;
      bvh.u[jp] = uh ^ 0x80000000u;            // (vr, -vi)
      bvl.u[jp] = ul ^ 0x80000000u;
      bvi.u[jp] = (uh >> 16) | (uh << 16);     // (vi, vr)
      bvj.u[jp] = (ul >> 16) | (ul << 16);
    }
#pragma unroll
    for (int mt = 0; mt < 2; ++mt) {
      int sidx = (mt * 16 + lid) * 64 + ((ks * 16 + grp * 4) ^ (lid << 2));
      U8 a2h, a2l;
      a2h.v = *(const bf16x8*)&Shi[sidx];
      a2l.v = *(const bf16x8*)&Slo[sidx];
      ore[mt] = __builtin_amdgcn_mfma_f32_16x16x32_bf16(a2h.v, bvh.v, ore[mt], 0, 0, 0);
      ore[mt] = __builtin_amdgcn_mfma_f32_16x16x32_bf16(a2l.v, bvh.v, ore[mt], 0, 0, 0);
      ore[mt] = __builtin_amdgcn_mfma_f32_16x16x32_bf16(a2h.v, bvl.v, ore[mt], 0, 0, 0);
      oim[mt] = __builtin_amdgcn_mfma_f32_16x16x32_bf16(a2h.v, bvi.v, oim[mt], 0, 0, 0);
      oim[mt] = __builtin_amdgcn_mfma_f32_16x16x32_bf16(a2l.v, bvi.v, oim[mt], 0, 0, 0);
      oim[mt] = __builtin_amdgcn_mfma_f32_16x16x32_bf16(a2h.v, bvj.v, oim[mt], 0, 0, 0);
    }
  }
  __syncthreads();                      // before next tile's S overwrite
}

__global__ __launch_bounds__(256, 3) void attn_kernel(
    const uint2* __restrict__ qf, const uint2* __restrict__ kf,
    const uint2* __restrict__ vfT, float2* __restrict__ of) {
  __shared__ __align__(16) unsigned char smem[16896];
  unsigned* Shi = (unsigned*)smem;              // [32 x][64 y] dw, swizzled
  unsigned* Slo = (unsigned*)(smem + 8192);
  float* zred = (float*)(smem + 16384);         // [4 w][32 x]

  int tid = threadIdx.x;
  int w = tid >> 6;                             // wave 0..3
  int lane = tid & 63;
  int grp = lane >> 4;                          // k-group 0..3
  int lid = lane & 15;

  unsigned v0 = blockIdx.x;                     // 0..2175
  unsigned cc = v0 & 7u;                        // XCD
  unsigned jj = v0 >> 3;                        // 0..271
  int bh = (int)(cc + 8u * (jj / 17u));
  int x0 = (int)(jj % 17u) * 32;

  const uint2* qb = qf + (size_t)bh * (64 * 514);
  const uint2* kb = kf + (size_t)bh * (64 * 514);
  const uint2* vb = vfT + (size_t)bh * (514 * 64);

  // ---- A fragments (q) direct from global (coalesced per quarter) ----
  U8 Ah[2][4], Al[2][4];
#pragma unroll
  for (int mt = 0; mt < 2; ++mt) {
    int gx = x0 + mt * 16 + lid;
    bool qv = gx < 514;
#pragma unroll
    for (int ks = 0; ks < 4; ++ks)
#pragma unroll
      for (int jp = 0; jp < 4; ++jp) {
        int e = ks * 16 + grp * 4 + jp;
        uint2 d = make_uint2(0, 0);
        if (qv) d = qb[(size_t)e * 514 + gx];
        Ah[mt][ks].u[jp] = d.x;
        Al[mt][ks].u[jp] = d.y;
      }
  }

  float zacc[8] = {0.f, 0.f, 0.f, 0.f, 0.f, 0.f, 0.f, 0.f};
  f32x4 ore[2] = {{0.f, 0.f, 0.f, 0.f}, {0.f, 0.f, 0.f, 0.f}};
  f32x4 oim[2] = {{0.f, 0.f, 0.f, 0.f}, {0.f, 0.f, 0.f, 0.f}};

#pragma unroll 1
  for (int yt = 0; yt < 8; ++yt)
    attn_tile<false>(yt * 64, kb, vb, Ah, Al, Shi, Slo, zacc, ore, oim,
                     w, grp, lid);
  attn_tile<true>(512, kb, vb, Ah, Al, Shi, Slo, zacc, ore, oim,
                  w, grp, lid);

  // ---- Z reduction: per-lane partials -> per-x totals ----
#pragma unroll
  for (int mt = 0; mt < 2; ++mt)
#pragma unroll
    for (int r = 0; r < 4; ++r) {
      float z = zacc[mt * 4 + r];
      z += __shfl_xor(z, 1); z += __shfl_xor(z, 2);
      z += __shfl_xor(z, 4); z += __shfl_xor(z, 8);
      zacc[mt * 4 + r] = z;
    }
  if (lid == 0) {
#pragma unroll
    for (int mt = 0; mt < 2; ++mt)
#pragma unroll
      for (int r = 0; r < 4; ++r)
        zred[w * 32 + mt * 16 + grp * 4 + r] = zacc[mt * 4 + r];
  }
  __syncthreads();
  // ---- normalize + stage output tile [64 e][32 x] (swz x ^ ((e&7)<<2)) ----
  float2* ov = (float2*)smem;           // aliases S planes (16 KB)
#pragma unroll
  for (int mt = 0; mt < 2; ++mt)
#pragma unroll
    for (int r = 0; r < 4; ++r) {
      int x = mt * 16 + grp * 4 + r;
      float z = zred[x] + zred[32 + x] + zred[64 + x] + zred[96 + x];
      float inv = 1.f / fmaxf(z, 1e-12f);
      int e = w * 16 + lid;
      ov[e * 32 + (x ^ ((e & 7) << 2))] =
          make_float2(ore[mt][r] * inv, oim[mt][r] * inv);
    }
  __syncthreads();
  // ---- coalesced write: of[(bh*64+e)*513 + x] ----
  {
    float2* ob = of + (size_t)bh * 64 * 513;
#pragma unroll
    for (int i = 0; i < 4; ++i) {
      int e = (tid >> 4) + i * 16;
      int xq = (tid & 15) * 2;
      int sw = (e & 7) << 2;
      float2 a = ov[e * 32 + (xq ^ sw)];
      float2 b2 = ov[e * 32 + ((xq + 1) ^ sw)];
      int gx = x0 + xq;
      if (gx < 513) ob[(size_t)e * 513 + gx] = a;
      if (gx + 1 < 513) ob[(size_t)e * 513 + gx + 1] = b2;
    }
  }
}

// ------- Inverse rfft (ortho), of stride 513 -> f32 out [B,L,H,E] -------
__global__ __launch_bounds__(256) void fft_inv_kernel(
    const float2* __restrict__ in, float* __restrict__ out) {
  __shared__ float2 sb0[1024];
  __shared__ float2 sb1[1024];
  __shared__ float2 twd[512];
  int tid = threadIdx.x;
  size_t r = blockIdx.x;                // (b*8+h)*64 + e
  const float2* ip = in + r * 513;
#pragma unroll
  for (int i = 0; i < 4; ++i) {
    int idx = tid + i * 256;
    float2 v;
    if (idx < 513) {
      v = ip[idx];
    } else {                            // Hermitian mirror
      float2 u = ip[1024 - idx];
      v = make_float2(u.x, -u.y);
    }
    sb0[idx] = v;
  }
  for (int kk = tid; kk < 512; kk += 256) {
    float ang = 6.283185307179586f * (float)kk * (1.0f / 1024.0f);
    float sn, cs;
    __sincosf(ang, &sn, &cs);
    twd[kk] = make_float2(cs, sn);
  }
  fft1024(sb0, sb1, twd, tid);
  int e = (int)(r & 63);
  int h = (int)((r >> 6) & 7);
  size_t b = r >> 9;
  float* op = out + b * (size_t)(1024 * 512) + (size_t)h * 64 + e;
  const float sc = 0.03125f;            // 1/sqrt(1024)
#pragma unroll
  for (int i = 0; i < 4; ++i) {
    int l = tid + i * 256;
    op[(size_t)l * 512] = sb0[l].x * sc;
  }
}

// ---------------- launch ------------------------------------------------
extern "C" void kernel_launch(void* const* d_in, const int* in_sizes, int n_in,
                              void* d_out, int out_size, void* d_ws, size_t ws_size,
                              hipStream_t stream) {
  const float* q = (const float*)d_in[0];
  const float* k = (const float*)d_in[1];
  const float* v = (const float*)d_in[2];
  const float* W = (const float*)d_in[3];
  const float* bias = (const float*)d_in[4];
  float* out = (float*)d_out;

  // Workspace map (float offsets), regions of 8,421,376 floats each:
  //   A   [0)         reused: q2t -> kT -> vT -> vfT
  //   QFR [8421376)   reused: XPhi+XPlo (split q) -> qf (bf16-split freq)
  //   R2  [16842752)  reused: Wsp (split W) -> vf -> of
  //   R3  [25264128)  kf
  float* wsf = (float*)d_ws;
  float*    A    = wsf;
  uint2*    vfT  = (uint2*)wsf;
  unsigned* XPhi = (unsigned*)(wsf + 8421376);
  unsigned* XPlo = XPhi + (size_t)16 * 1024 * 256;   // +16 MB
  ushort4*  qf   = (ushort4*)(wsf + 8421376);
  uint2*    Wsp  = (uint2*)(wsf + 16842752);
  ushort4*  vf   = (ushort4*)(wsf + 16842752);
  float2*   of   = (float2*)(wsf + 16842752);        // overwrites vf
  ushort4*  kf   = (ushort4*)(wsf + 25264128);

  transpose_q_split<<<dim3(32, 16, 16), 256, 0, stream>>>(q, XPhi, XPlo);
  transpose_w_split<<<dim3(32, 32), 256, 0, stream>>>(W, Wsp);
  conv_glu_mfma<<<dim3(2048), 256, 0, stream>>>(XPhi, XPlo, Wsp, bias, A);
  fft_fwd_kernel<<<dim3(8192), 256, 0, stream>>>(A, qf, 0.03125f * 0.125f);
  transpose_kernel<<<dim3(32, 16, 16), 256, 0, stream>>>(k, A);
  fft_fwd_kernel<<<dim3(8192), 256, 0, stream>>>(A, kf, 0.03125f);
  transpose_kernel<<<dim3(32, 16, 16), 256, 0, stream>>>(v, A);
  fft_fwd_kernel<<<dim3(8192), 256, 0, stream>>>(A, vf, 0.03125f);
  vft_kernel<<<dim3(9, 128), 256, 0, stream>>>((const uint2*)vf, vfT);
  attn_kernel<<<dim3(2176), 256, 0, stream>>>((const uint2*)qf, (const uint2*)kf,
                                              vfT, of);
  fft_inv_kernel<<<dim3(8192), 256, 0, stream>>>(of, out);
}

// Round 7
// 831.862 us; speedup vs baseline: 1.0743x; 1.0743x over previous
//
#include <hip/hip_runtime.h>
#include <math.h>

// Problem: B=16, L=S=1024, H=8, E=64, d=512, Lf=513 (freq rows PADDED to 514)
// Pipeline: split-transpose(q) -> split-repack(W) -> conv+GLU (MFMA v4,
//           LDS-free / barrier-free) -> rfft(q2) -> transpose(k) -> rfft ->
//           transpose(v) -> rfft -> vf-transpose -> attn(MFMA, L2-direct K/V)
//           -> irfft
// All matmul-shaped compute runs on mfma_f32_16x16x32_bf16 with a 3-product
// error-compensated hi/lo split (~2^-17 per product; below f32-FFT floor).
// conv v4: r4 tile (M=64 og, N=256 l, grid 1024) but A-fragments (W) loaded
// DIRECTLY from global (coalesced b64, L1-served across waves) -> no LDS,
// no barriers in the K-loop, no bank conflicts. r5 (hand pipeline -> spills)
// and r6 (half tile -> staging amortization loss) both regressed vs this.
// Workspace: 4 regions x 8,421,376 floats = 134,742,016 bytes.

typedef __attribute__((ext_vector_type(8))) short bf16x8;
typedef __attribute__((ext_vector_type(4))) float f32x4;

union U8 { bf16x8 v; unsigned u[4]; };

__device__ __forceinline__ unsigned short f2b(float x) {  // f32 -> bf16 RNE
  unsigned u = __float_as_uint(x);
  return (unsigned short)((u + 0x7FFFu + ((u >> 16) & 1u)) >> 16);
}
__device__ __forceinline__ float b2f(unsigned short h) {
  return __uint_as_float(((unsigned)h) << 16);
}
__device__ __forceinline__ unsigned cvtpk_bf16(float lo, float hi) {
  unsigned r;  // dst.lo16 = bf16(lo), dst.hi16 = bf16(hi)
  asm("v_cvt_pk_bf16_f32 %0, %1, %2" : "=v"(r) : "v"(lo), "v"(hi));
  return r;
}

// ---------------- Stockham FFT core, N=1024, 256 threads ----------------
__device__ __forceinline__ void fft1024(float2* b0, float2* b1,
                                        const float2* twd, int tid) {
  float2* src = b0;
  float2* dst = b1;
#pragma unroll
  for (int st = 0; st < 10; ++st) {
    __syncthreads();
#pragma unroll
    for (int qq = 0; qq < 2; ++qq) {
      int bi = tid + qq * 256;          // butterfly index in [0,512)
      int m = 1 << st;
      int j = bi >> st;
      int jm = j << st;
      float2 c0 = src[bi];
      float2 c1 = src[bi + 512];
      float2 w = twd[jm];
      float2 sum, dif, tw;
      sum.x = c0.x + c1.x; sum.y = c0.y + c1.y;
      dif.x = c0.x - c1.x; dif.y = c0.y - c1.y;
      tw.x = dif.x * w.x - dif.y * w.y;
      tw.y = dif.x * w.y + dif.y * w.x;
      dst[bi + jm] = sum;
      dst[bi + jm + m] = tw;
    }
    float2* tmp = src; src = dst; dst = tmp;
  }
  __syncthreads();
}

// ---------------- transpose: f32 [B][1024][512] -> f32 [B][512][1024] ---
__global__ __launch_bounds__(256) void transpose_kernel(
    const float* __restrict__ in, float* __restrict__ out) {
  __shared__ float tile[32][33];
  int b = blockIdx.z;
  int s0 = blockIdx.x * 32;
  int c0 = blockIdx.y * 32;
  int tx = threadIdx.x & 31;
  int ty = threadIdx.x >> 5;            // 0..7
  const float* ip = in + (size_t)b * (1024 * 512);
  float* op = out + (size_t)b * (1024 * 512);
#pragma unroll
  for (int i = 0; i < 32; i += 8)
    tile[ty + i][tx] = ip[(size_t)(s0 + ty + i) * 512 + c0 + tx];
  __syncthreads();
#pragma unroll
  for (int i = 0; i < 32; i += 8)
    op[(size_t)(c0 + ty + i) * 1024 + s0 + tx] = tile[tx][ty + i];
}

// ------- q split-transpose: f32 [B][1024 l][512 c] -> bf16-split pair ---
__global__ __launch_bounds__(256) void transpose_q_split(
    const float* __restrict__ in, unsigned* __restrict__ XPhi,
    unsigned* __restrict__ XPlo) {
  __shared__ float tile[32][33];
  int b = blockIdx.z;
  int l0 = blockIdx.x * 32;
  int c0 = blockIdx.y * 32;
  int tx = threadIdx.x & 31;
  int ty = threadIdx.x >> 5;            // 0..7
  const float* ip = in + (size_t)b * (1024 * 512);
#pragma unroll
  for (int i = 0; i < 32; i += 8)
    tile[ty + i][tx] = ip[(size_t)(l0 + ty + i) * 512 + c0 + tx];
  __syncthreads();
  int p = threadIdx.x & 15;
  int lb = threadIdx.x >> 4;            // 0..15
#pragma unroll
  for (int i = 0; i < 2; ++i) {
    int ll = lb + i * 16;
    float v0 = tile[ll][2 * p];
    float v1 = tile[ll][2 * p + 1];
    unsigned short h0 = f2b(v0), h1 = f2b(v1);
    unsigned short q0 = f2b(v0 - b2f(h0)), q1 = f2b(v1 - b2f(h1));
    size_t o = ((size_t)b * 1024 + l0 + ll) * 256 + (c0 >> 1) + p;
    XPhi[o] = (unsigned)h0 | ((unsigned)h1 << 16);
    XPlo[o] = (unsigned)q0 | ((unsigned)q1 << 16);
  }
}

// ------- W split-repack: [1024 og][512 c][3 t] f32 ->
//         Wsp[(p*3+t)*1024 + og] uint2 {hi_pair, lo_pair}, p = c/2 -------
__global__ __launch_bounds__(256) void transpose_w_split(
    const float* __restrict__ Win, uint2* __restrict__ Wsp) {
  __shared__ float tile[32][49];        // [og][48 ct = 8 pairs x 3 t x 2]
  int og0 = blockIdx.x * 32;
  int ct0 = blockIdx.y * 48;
  int tid = threadIdx.x;
#pragma unroll
  for (int i = 0; i < 6; ++i) {
    int flat = tid + i * 256;
    int og = flat / 48, ct = flat % 48;
    tile[og][ct] = Win[(size_t)(og0 + og) * 1536 + ct0 + ct];
  }
  __syncthreads();
  int ogl = tid & 31;
  int s = tid >> 5;                     // 0..7
#pragma unroll
  for (int i = 0; i < 3; ++i) {
    int pt = s + i * 8;                 // 0..23
    int pl = pt / 3, t = pt % 3;
    float v0 = tile[ogl][pl * 6 + t];       // c = 2*(ct0/6 + pl)
    float v1 = tile[ogl][pl * 6 + 3 + t];   // c+1
    unsigned short h0 = f2b(v0), h1 = f2b(v1);
    unsigned short q0 = f2b(v0 - b2f(h0)), q1 = f2b(v1 - b2f(h1));
    Wsp[((size_t)(ct0 / 6 + pl) * 3 + t) * 1024 + og0 + ogl] =
        make_uint2((unsigned)h0 | ((unsigned)h1 << 16),
                   (unsigned)q0 | ((unsigned)q1 << 16));
  }
}

// ------- Conv1d(512->1024,k=3,pad=1) + GLU via MFMA v4 ------------------
// GEMM: C[og][l] = sum_{c,t} W[og][c][t] * X[c][l+t-1]; per block M=64 og,
// N=256 l (4 waves x 64), K=512c x 3t, 3-product hi/lo split. LDS-free:
// A-fragments (W) loaded directly from Wsp (coalesced b64 per quarter-wave;
// all 4 waves read the same addresses -> L1 hits). NO barriers in K-loop.
// Grid 1024 = 16 b x 16 ca x 4 l, XCD-swizzled (each XCD owns 2 batches).
__global__ __launch_bounds__(256, 2) void conv_glu_mfma(
    const unsigned* __restrict__ XPhi, const unsigned* __restrict__ XPlo,
    const uint2* __restrict__ Wsp, const float* __restrict__ bias,
    float* __restrict__ q2t) {
  int tid = threadIdx.x;
  int w = tid >> 6;                     // wave 0..3
  int lane = tid & 63;
  int grp = lane >> 4;                  // k-group 0..3
  int lid = lane & 15;

  unsigned v0 = blockIdx.x;             // 0..1023
  int xcd = (int)(v0 & 7u);
  int j = (int)(v0 >> 3);               // 0..127
  int b = xcd * 2 + (j >> 6);
  int rem = j & 63;
  int ca = (rem >> 2) * 32;             // GLU channel base
  int l0 = (rem & 3) * 256;             // l base

  const unsigned* xh = XPhi + (size_t)b * 1024 * 256;
  const unsigned* xl = XPlo + (size_t)b * 1024 * 256;

  int lbase = l0 + w * 64 + lid;        // + ni*16 + t - 1 per fragment

  // per-mi W row (og): mi 0,1 = a-rows (ca+ogi), mi 2,3 = g-rows (512+...)
  int ogm[4];
#pragma unroll
  for (int mi = 0; mi < 4; ++mi) {
    int ogi = mi * 16 + lid;
    ogm[mi] = (ogi < 32) ? (ca + ogi) : (480 + ca + ogi);
  }

  f32x4 acc[4][4];
#pragma unroll
  for (int mi = 0; mi < 4; ++mi)
#pragma unroll
    for (int ni = 0; ni < 4; ++ni) acc[mi][ni] = {0.f, 0.f, 0.f, 0.f};

#pragma unroll 1
  for (int c0 = 0; c0 < 512; c0 += 32) {
    int pb = (c0 >> 1) + 4 * grp;       // this lane's pair base in the tile
#pragma unroll
    for (int t = 0; t < 3; ++t) {
      // ---- B fragments (X) from global, predicated for pad ----
      U8 Bh[4], Bl[4];
#pragma unroll
      for (int ni = 0; ni < 4; ++ni) {
        unsigned gl = (unsigned)(lbase + ni * 16 + t - 1);
        uint4 dh = make_uint4(0, 0, 0, 0), dl = make_uint4(0, 0, 0, 0);
        if (gl < 1024u) {
          size_t off = (size_t)gl * 256 + pb;
          dh = *(const uint4*)(xh + off);
          dl = *(const uint4*)(xl + off);
        }
        Bh[ni].u[0] = dh.x; Bh[ni].u[1] = dh.y;
        Bh[ni].u[2] = dh.z; Bh[ni].u[3] = dh.w;
        Bl[ni].u[0] = dl.x; Bl[ni].u[1] = dl.y;
        Bl[ni].u[2] = dl.z; Bl[ni].u[3] = dl.w;
      }
      // ---- A fragments (W) direct from global; MFMA ----
#pragma unroll
      for (int mi = 0; mi < 4; ++mi) {
        U8 Ah, Al;
#pragma unroll
        for (int jp = 0; jp < 4; ++jp) {
          uint2 g = Wsp[((size_t)(pb + jp) * 3 + t) * 1024 + ogm[mi]];
          Ah.u[jp] = g.x;
          Al.u[jp] = g.y;
        }
#pragma unroll
        for (int ni = 0; ni < 4; ++ni) {
          acc[mi][ni] = __builtin_amdgcn_mfma_f32_16x16x32_bf16(
              Ah.v, Bl[ni].v, acc[mi][ni], 0, 0, 0);
          acc[mi][ni] = __builtin_amdgcn_mfma_f32_16x16x32_bf16(
              Al.v, Bh[ni].v, acc[mi][ni], 0, 0, 0);
          acc[mi][ni] = __builtin_amdgcn_mfma_f32_16x16x32_bf16(
              Ah.v, Bh[ni].v, acc[mi][ni], 0, 0, 0);
        }
      }
    }
  }

  // epilogue: GLU is lane-local (a at mi, g at mi+2, same lane)
#pragma unroll
  for (int mi = 0; mi < 2; ++mi)
#pragma unroll
    for (int rr = 0; rr < 4; ++rr) {
      int row = mi * 16 + grp * 4 + rr;     // 0..31
      float ba = bias[ca + row];
      float bg = bias[512 + ca + row];
      float* orow =
          q2t + ((size_t)b * 512 + ca + row) * 1024 + l0 + w * 64 + lid;
#pragma unroll
      for (int ni = 0; ni < 4; ++ni) {
        float a = acc[mi][ni][rr] + ba;
        float g = acc[mi + 2][ni][rr] + bg;
        orow[ni * 16] = a / (1.f + __expf(-g));
      }
    }
}

// ------- Forward rfft: f32 row [1024] -> 513 bf16-split complex ---------
__global__ __launch_bounds__(256) void fft_fwd_kernel(
    const float* __restrict__ in, ushort4* __restrict__ out, float scale) {
  __shared__ float2 sb0[1024];
  __shared__ float2 sb1[1024];
  __shared__ float2 twd[512];
  int tid = threadIdx.x;
  size_t r = blockIdx.x;                // row = (b*8+h)*64 + e
  const float* ip = in + r * 1024;
#pragma unroll
  for (int i = 0; i < 4; ++i) {
    int idx = tid + i * 256;
    sb0[idx] = make_float2(ip[idx], 0.f);
  }
  for (int kk = tid; kk < 512; kk += 256) {
    float ang = -6.283185307179586f * (float)kk * (1.0f / 1024.0f);
    float sn, cs;
    __sincosf(ang, &sn, &cs);
    twd[kk] = make_float2(cs, sn);
  }
  fft1024(sb0, sb1, twd, tid);
  ushort4* op = out + r * 514;          // padded row stride
  for (int x = tid; x < 513; x += 256) {
    float2 v = sb0[x];
    float re = v.x * scale, im = v.y * scale;
    unsigned short rh = f2b(re), ih = f2b(im);
    unsigned short rl = f2b(re - b2f(rh)), il = f2b(im - b2f(ih));
    op[x] = make_ushort4(rh, ih, rl, il);
  }
  if (tid == 0) op[513] = make_ushort4(0, 0, 0, 0);
}

// ------- vf transpose: [bh][64 e][514 y] uint2 -> vfT [bh][514 y][64 e] --
__global__ __launch_bounds__(256) void vft_kernel(
    const uint2* __restrict__ vf, uint2* __restrict__ vfT) {
  __shared__ uint2 tile[64][65];
  int bh = blockIdx.y;
  int y0 = blockIdx.x * 64;
  int tid = threadIdx.x;
  const uint2* src = vf + (size_t)bh * 64 * 514;
  uint2* dst = vfT + (size_t)bh * 514 * 64;
#pragma unroll
  for (int i = 0; i < 16; ++i) {
    int flat = tid + i * 256;
    int e = flat >> 6, y = flat & 63;
    int gy = y0 + y;
    uint2 d = make_uint2(0, 0);
    if (gy < 514) d = src[(size_t)e * 514 + gy];
    tile[e][y] = d;
  }
  __syncthreads();
#pragma unroll
  for (int i = 0; i < 16; ++i) {
    int flat = tid + i * 256;
    int y = flat >> 6, e = flat & 63;
    int gy = y0 + y;
    if (gy < 514) dst[(size_t)gy * 64 + e] = tile[e][y];
  }
}

// ---------------- Fused frequency attention v3 (MFMA, L2-direct K/V) -----
template <bool TAIL>
__device__ __forceinline__ void attn_tile(
    int y0, const uint2* __restrict__ kb, const uint2* __restrict__ vb,
    const U8 (&Ah)[2][4], const U8 (&Al)[2][4],
    unsigned* Shi, unsigned* Slo, float* zacc, f32x4* ore, f32x4* oim,
    int w, int grp, int lid) {
  int yk = y0 + 16 * w + lid;           // GEMM1 column owned by this lane
  uint2 BK[4][4];
  bool kval = !TAIL || (yk < 514);
#pragma unroll
  for (int ks = 0; ks < 4; ++ks)
#pragma unroll
    for (int jp = 0; jp < 4; ++jp) {
      int e = ks * 16 + grp * 4 + jp;
      if (!TAIL) {
        BK[ks][jp] = kb[(size_t)e * 514 + yk];
      } else {
        uint2 d = make_uint2(0, 0);
        if (kval) d = kb[(size_t)e * 514 + yk];
        BK[ks][jp] = d;
      }
    }
  f32x4 cre[2] = {{0.f, 0.f, 0.f, 0.f}, {0.f, 0.f, 0.f, 0.f}};
  f32x4 cim[2] = {{0.f, 0.f, 0.f, 0.f}, {0.f, 0.f, 0.f, 0.f}};
#pragma unroll
  for (int ks = 0; ks < 4; ++ks) {
    U8 bhh, bll, bih, bil;
#pragma unroll
    for (int jp = 0; jp < 4; ++jp) {
      unsigned uh = BK[ks][jp].x, ul = BK[ks][jp].y;
      bhh.u[jp] = uh;                                  // (kr, ki)
      bll.u[jp] = ul;
      bih.u[jp] = ((uh >> 16) ^ 0x8000u) | (uh << 16); // (-ki, kr)
      bil.u[jp] = ((ul >> 16) ^ 0x8000u) | (ul << 16);
    }
#pragma unroll
    for (int mt = 0; mt < 2; ++mt) {
      cre[mt] = __builtin_amdgcn_mfma_f32_16x16x32_bf16(Ah[mt][ks].v, bhh.v, cre[mt], 0, 0, 0);
      cre[mt] = __builtin_amdgcn_mfma_f32_16x16x32_bf16(Al[mt][ks].v, bhh.v, cre[mt], 0, 0, 0);
      cre[mt] = __builtin_amdgcn_mfma_f32_16x16x32_bf16(Ah[mt][ks].v, bll.v, cre[mt], 0, 0, 0);
      cim[mt] = __builtin_amdgcn_mfma_f32_16x16x32_bf16(Ah[mt][ks].v, bih.v, cim[mt], 0, 0, 0);
      cim[mt] = __builtin_amdgcn_mfma_f32_16x16x32_bf16(Al[mt][ks].v, bih.v, cim[mt], 0, 0, 0);
      cim[mt] = __builtin_amdgcn_mfma_f32_16x16x32_bf16(Ah[mt][ks].v, bil.v, cim[mt], 0, 0, 0);
    }
  }
  // ---- gate + L1 partial + split scores to LDS ----
#pragma unroll
  for (int mt = 0; mt < 2; ++mt)
#pragma unroll
    for (int r = 0; r < 4; ++r) {
      float sre = cre[mt][r], sim = cim[mt][r];
      float m = sqrtf(sre * sre + sim * sim);
      float f = 1.f + 1.f / (1.f + __expf(-m));
      zacc[mt * 4 + r] += m * f;
      float wre = sre * f, wim = sim * f;
      unsigned dh = cvtpk_bf16(wre, wim);
      float rre = wre - __uint_as_float(dh << 16);
      float rim = wim - __uint_as_float(dh & 0xffff0000u);
      unsigned dl = cvtpk_bf16(rre, rim);
      int x = mt * 16 + grp * 4 + r;
      int idx = x * 64 + ((16 * w + lid) ^ ((x & 15) << 2));
      Shi[idx] = dh;
      Slo[idx] = dl;
    }
  __syncthreads();
  // ---- GEMM2: of[x][e] += sc * vf ----
#pragma unroll
  for (int ks = 0; ks < 4; ++ks) {
    uint2 BV[4];
#pragma unroll
    for (int jp = 0; jp < 4; ++jp) {
      int yv = y0 + ks * 16 + grp * 4 + jp;
      if (!TAIL) {
        BV[jp] = vb[(size_t)yv * 64 + 16 * w + lid];
      } else {
        uint2 d = make_uint2(0, 0);
        if (yv < 514) d = vb[(size_t)yv * 64 + 16 * w + lid];
        BV[jp] = d;
      }
    }
    U8 bvh, bvl, bvi, bvj;
#pragma unroll
    for (int jp = 0; jp < 4; ++jp) {
      unsigned uh = BV[jp].x, ul = BV[jp].y;
      bvh.u[jp] = uh ^ 0x80000000u;            // (vr, -vi)
      bvl.u[jp] = ul ^ 0x80000000u;
      bvi.u[jp] = (uh >> 16) | (uh << 16);     // (vi, vr)
      bvj.u[jp] = (ul >> 16) | (ul << 16);
    }
#pragma unroll
    for (int mt = 0; mt < 2; ++mt) {
      int sidx = (mt * 16 + lid) * 64 + ((ks * 16 + grp * 4) ^ (lid << 2));
      U8 a2h, a2l;
      a2h.v = *(const bf16x8*)&Shi[sidx];
      a2l.v = *(const bf16x8*)&Slo[sidx];
      ore[mt] = __builtin_amdgcn_mfma_f32_16x16x32_bf16(a2h.v, bvh.v, ore[mt], 0, 0, 0);
      ore[mt] = __builtin_amdgcn_mfma_f32_16x16x32_bf16(a2l.v, bvh.v, ore[mt], 0, 0, 0);
      ore[mt] = __builtin_amdgcn_mfma_f32_16x16x32_bf16(a2h.v, bvl.v, ore[mt], 0, 0, 0);
      oim[mt] = __builtin_amdgcn_mfma_f32_16x16x32_bf16(a2h.v, bvi.v, oim[mt], 0, 0, 0);
      oim[mt] = __builtin_amdgcn_mfma_f32_16x16x32_bf16(a2l.v, bvi.v, oim[mt], 0, 0, 0);
      oim[mt] = __builtin_amdgcn_mfma_f32_16x16x32_bf16(a2h.v, bvj.v, oim[mt], 0, 0, 0);
    }
  }
  __syncthreads();                      // before next tile's S overwrite
}

__global__ __launch_bounds__(256, 3) void attn_kernel(
    const uint2* __restrict__ qf, const uint2* __restrict__ kf,
    const uint2* __restrict__ vfT, float2* __restrict__ of) {
  __shared__ __align__(16) unsigned char smem[16896];
  unsigned* Shi = (unsigned*)smem;              // [32 x][64 y] dw, swizzled
  unsigned* Slo = (unsigned*)(smem + 8192);
  float* zred = (float*)(smem + 16384);         // [4 w][32 x]

  int tid = threadIdx.x;
  int w = tid >> 6;                             // wave 0..3
  int lane = tid & 63;
  int grp = lane >> 4;                          // k-group 0..3
  int lid = lane & 15;

  unsigned v0 = blockIdx.x;                     // 0..2175
  unsigned cc = v0 & 7u;                        // XCD
  unsigned jj = v0 >> 3;                        // 0..271
  int bh = (int)(cc + 8u * (jj / 17u));
  int x0 = (int)(jj % 17u) * 32;

  const uint2* qb = qf + (size_t)bh * (64 * 514);
  const uint2* kb = kf + (size_t)bh * (64 * 514);
  const uint2* vb = vfT + (size_t)bh * (514 * 64);

  // ---- A fragments (q) direct from global (coalesced per quarter) ----
  U8 Ah[2][4], Al[2][4];
#pragma unroll
  for (int mt = 0; mt < 2; ++mt) {
    int gx = x0 + mt * 16 + lid;
    bool qv = gx < 514;
#pragma unroll
    for (int ks = 0; ks < 4; ++ks)
#pragma unroll
      for (int jp = 0; jp < 4; ++jp) {
        int e = ks * 16 + grp * 4 + jp;
        uint2 d = make_uint2(0, 0);
        if (qv) d = qb[(size_t)e * 514 + gx];
        Ah[mt][ks].u[jp] = d.x;
        Al[mt][ks].u[jp] = d.y;
      }
  }

  float zacc[8] = {0.f, 0.f, 0.f, 0.f, 0.f, 0.f, 0.f, 0.f};
  f32x4 ore[2] = {{0.f, 0.f, 0.f, 0.f}, {0.f, 0.f, 0.f, 0.f}};
  f32x4 oim[2] = {{0.f, 0.f, 0.f, 0.f}, {0.f, 0.f, 0.f, 0.f}};

#pragma unroll 1
  for (int yt = 0; yt < 8; ++yt)
    attn_tile<false>(yt * 64, kb, vb, Ah, Al, Shi, Slo, zacc, ore, oim,
                     w, grp, lid);
  attn_tile<true>(512, kb, vb, Ah, Al, Shi, Slo, zacc, ore, oim,
                  w, grp, lid);

  // ---- Z reduction: per-lane partials -> per-x totals ----
#pragma unroll
  for (int mt = 0; mt < 2; ++mt)
#pragma unroll
    for (int r = 0; r < 4; ++r) {
      float z = zacc[mt * 4 + r];
      z += __shfl_xor(z, 1); z += __shfl_xor(z, 2);
      z += __shfl_xor(z, 4); z += __shfl_xor(z, 8);
      zacc[mt * 4 + r] = z;
    }
  if (lid == 0) {
#pragma unroll
    for (int mt = 0; mt < 2; ++mt)
#pragma unroll
      for (int r = 0; r < 4; ++r)
        zred[w * 32 + mt * 16 + grp * 4 + r] = zacc[mt * 4 + r];
  }
  __syncthreads();
  // ---- normalize + stage output tile [64 e][32 x] (swz x ^ ((e&7)<<2)) ----
  float2* ov = (float2*)smem;           // aliases S planes (16 KB)
#pragma unroll
  for (int mt = 0; mt < 2; ++mt)
#pragma unroll
    for (int r = 0; r < 4; ++r) {
      int x = mt * 16 + grp * 4 + r;
      float z = zred[x] + zred[32 + x] + zred[64 + x] + zred[96 + x];
      float inv = 1.f / fmaxf(z, 1e-12f);
      int e = w * 16 + lid;
      ov[e * 32 + (x ^ ((e & 7) << 2))] =
          make_float2(ore[mt][r] * inv, oim[mt][r] * inv);
    }
  __syncthreads();
  // ---- coalesced write: of[(bh*64+e)*513 + x] ----
  {
    float2* ob = of + (size_t)bh * 64 * 513;
#pragma unroll
    for (int i = 0; i < 4; ++i) {
      int e = (tid >> 4) + i * 16;
      int xq = (tid & 15) * 2;
      int sw = (e & 7) << 2;
      float2 a = ov[e * 32 + (xq ^ sw)];
      float2 b2 = ov[e * 32 + ((xq + 1) ^ sw)];
      int gx = x0 + xq;
      if (gx < 513) ob[(size_t)e * 513 + gx] = a;
      if (gx + 1 < 513) ob[(size_t)e * 513 + gx + 1] = b2;
    }
  }
}

// ------- Inverse rfft (ortho), of stride 513 -> f32 out [B,L,H,E] -------
__global__ __launch_bounds__(256) void fft_inv_kernel(
    const float2* __restrict__ in, float* __restrict__ out) {
  __shared__ float2 sb0[1024];
  __shared__ float2 sb1[1024];
  __shared__ float2 twd[512];
  int tid = threadIdx.x;
  size_t r = blockIdx.x;                // (b*8+h)*64 + e
  const float2* ip = in + r * 513;
#pragma unroll
  for (int i = 0; i < 4; ++i) {
    int idx = tid + i * 256;
    float2 v;
    if (idx < 513) {
      v = ip[idx];
    } else {                            // Hermitian mirror
      float2 u = ip[1024 - idx];
      v = make_float2(u.x, -u.y);
    }
    sb0[idx] = v;
  }
  for (int kk = tid; kk < 512; kk += 256) {
    float ang = 6.283185307179586f * (float)kk * (1.0f / 1024.0f);
    float sn, cs;
    __sincosf(ang, &sn, &cs);
    twd[kk] = make_float2(cs, sn);
  }
  fft1024(sb0, sb1, twd, tid);
  int e = (int)(r & 63);
  int h = (int)((r >> 6) & 7);
  size_t b = r >> 9;
  float* op = out + b * (size_t)(1024 * 512) + (size_t)h * 64 + e;
  const float sc = 0.03125f;            // 1/sqrt(1024)
#pragma unroll
  for (int i = 0; i < 4; ++i) {
    int l = tid + i * 256;
    op[(size_t)l * 512] = sb0[l].x * sc;
  }
}

// ---------------- launch ------------------------------------------------
extern "C" void kernel_launch(void* const* d_in, const int* in_sizes, int n_in,
                              void* d_out, int out_size, void* d_ws, size_t ws_size,
                              hipStream_t stream) {
  const float* q = (const float*)d_in[0];
  const float* k = (const float*)d_in[1];
  const float* v = (const float*)d_in[2];
  const float* W = (const float*)d_in[3];
  const float* bias = (const float*)d_in[4];
  float* out = (float*)d_out;

  // Workspace map (float offsets), regions of 8,421,376 floats each:
  //   A   [0)         reused: q2t -> kT -> vT -> vfT
  //   QFR [8421376)   reused: XPhi+XPlo (split q) -> qf (bf16-split freq)
  //   R2  [16842752)  reused: Wsp (split W) -> vf -> of
  //   R3  [25264128)  kf
  float* wsf = (float*)d_ws;
  float*    A    = wsf;
  uint2*    vfT  = (uint2*)wsf;
  unsigned* XPhi = (unsigned*)(wsf + 8421376);
  unsigned* XPlo = XPhi + (size_t)16 * 1024 * 256;   // +16 MB
  ushort4*  qf   = (ushort4*)(wsf + 8421376);
  uint2*    Wsp  = (uint2*)(wsf + 16842752);
  ushort4*  vf   = (ushort4*)(wsf + 16842752);
  float2*   of   = (float2*)(wsf + 16842752);        // overwrites vf
  ushort4*  kf   = (ushort4*)(wsf + 25264128);

  transpose_q_split<<<dim3(32, 16, 16), 256, 0, stream>>>(q, XPhi, XPlo);
  transpose_w_split<<<dim3(32, 32), 256, 0, stream>>>(W, Wsp);
  conv_glu_mfma<<<dim3(1024), 256, 0, stream>>>(XPhi, XPlo, Wsp, bias, A);
  fft_fwd_kernel<<<dim3(8192), 256, 0, stream>>>(A, qf, 0.03125f * 0.125f);
  transpose_kernel<<<dim3(32, 16, 16), 256, 0, stream>>>(k, A);
  fft_fwd_kernel<<<dim3(8192), 256, 0, stream>>>(A, kf, 0.03125f);
  transpose_kernel<<<dim3(32, 16, 16), 256, 0, stream>>>(v, A);
  fft_fwd_kernel<<<dim3(8192), 256, 0, stream>>>(A, vf, 0.03125f);
  vft_kernel<<<dim3(9, 128), 256, 0, stream>>>((const uint2*)vf, vfT);
  attn_kernel<<<dim3(2176), 256, 0, stream>>>((const uint2*)qf, (const uint2*)kf,
                                              vfT, of);
  fft_inv_kernel<<<dim3(8192), 256, 0, stream>>>(of, out);
}

// Round 8
// 763.077 us; speedup vs baseline: 1.1712x; 1.0901x over previous
//
#include <hip/hip_runtime.h>
#include <math.h>

// Problem: B=16, L=S=1024, H=8, E=64, d=512, Lf=513 (freq rows PADDED to 514)
// Pipeline: split-transpose(q) -> split-repack(W) -> conv+GLU (MFMA v5,
//           8-wave blocks) -> rfft(q2) -> transpose(k) -> rfft ->
//           transpose(v) -> rfft -> vf-transpose -> attn(MFMA, L2-direct K/V)
//           -> irfft
// All matmul-shaped compute runs on mfma_f32_16x16x32_bf16 with a 3-product
// error-compensated hi/lo split (~2^-17 per product; below f32-FFT floor).
// conv v5: r4 block tile (64 og x 256 l, W in LDS, grid 1024) but 512-thread
// blocks with per-wave acc 4x2 (~108 unified regs, launch_bounds(512,4))
// -> 16 waves/CU (4/SIMD) instead of r4's 8 -- 2x TLP at identical traffic.
// History: r5 hand-pipeline spilled (274); r6 small-tile TLP doubled W-fetch
// (353); r7 LDS-free exposed raw latency (298); r4 baseline 241.
// Workspace: 4 regions x 8,421,376 floats = 134,742,016 bytes.

typedef __attribute__((ext_vector_type(8))) short bf16x8;
typedef __attribute__((ext_vector_type(4))) float f32x4;

union U8 { bf16x8 v; unsigned u[4]; };

__device__ __forceinline__ unsigned short f2b(float x) {  // f32 -> bf16 RNE
  unsigned u = __float_as_uint(x);
  return (unsigned short)((u + 0x7FFFu + ((u >> 16) & 1u)) >> 16);
}
__device__ __forceinline__ float b2f(unsigned short h) {
  return __uint_as_float(((unsigned)h) << 16);
}
__device__ __forceinline__ unsigned cvtpk_bf16(float lo, float hi) {
  unsigned r;  // dst.lo16 = bf16(lo), dst.hi16 = bf16(hi)
  asm("v_cvt_pk_bf16_f32 %0, %1, %2" : "=v"(r) : "v"(lo), "v"(hi));
  return r;
}

// ---------------- Stockham FFT core, N=1024, 256 threads ----------------
__device__ __forceinline__ void fft1024(float2* b0, float2* b1,
                                        const float2* twd, int tid) {
  float2* src = b0;
  float2* dst = b1;
#pragma unroll
  for (int st = 0; st < 10; ++st) {
    __syncthreads();
#pragma unroll
    for (int qq = 0; qq < 2; ++qq) {
      int bi = tid + qq * 256;          // butterfly index in [0,512)
      int m = 1 << st;
      int j = bi >> st;
      int jm = j << st;
      float2 c0 = src[bi];
      float2 c1 = src[bi + 512];
      float2 w = twd[jm];
      float2 sum, dif, tw;
      sum.x = c0.x + c1.x; sum.y = c0.y + c1.y;
      dif.x = c0.x - c1.x; dif.y = c0.y - c1.y;
      tw.x = dif.x * w.x - dif.y * w.y;
      tw.y = dif.x * w.y + dif.y * w.x;
      dst[bi + jm] = sum;
      dst[bi + jm + m] = tw;
    }
    float2* tmp = src; src = dst; dst = tmp;
  }
  __syncthreads();
}

// ---------------- transpose: f32 [B][1024][512] -> f32 [B][512][1024] ---
__global__ __launch_bounds__(256) void transpose_kernel(
    const float* __restrict__ in, float* __restrict__ out) {
  __shared__ float tile[32][33];
  int b = blockIdx.z;
  int s0 = blockIdx.x * 32;
  int c0 = blockIdx.y * 32;
  int tx = threadIdx.x & 31;
  int ty = threadIdx.x >> 5;            // 0..7
  const float* ip = in + (size_t)b * (1024 * 512);
  float* op = out + (size_t)b * (1024 * 512);
#pragma unroll
  for (int i = 0; i < 32; i += 8)
    tile[ty + i][tx] = ip[(size_t)(s0 + ty + i) * 512 + c0 + tx];
  __syncthreads();
#pragma unroll
  for (int i = 0; i < 32; i += 8)
    op[(size_t)(c0 + ty + i) * 1024 + s0 + tx] = tile[tx][ty + i];
}

// ------- q split-transpose: f32 [B][1024 l][512 c] -> bf16-split pair ---
__global__ __launch_bounds__(256) void transpose_q_split(
    const float* __restrict__ in, unsigned* __restrict__ XPhi,
    unsigned* __restrict__ XPlo) {
  __shared__ float tile[32][33];
  int b = blockIdx.z;
  int l0 = blockIdx.x * 32;
  int c0 = blockIdx.y * 32;
  int tx = threadIdx.x & 31;
  int ty = threadIdx.x >> 5;            // 0..7
  const float* ip = in + (size_t)b * (1024 * 512);
#pragma unroll
  for (int i = 0; i < 32; i += 8)
    tile[ty + i][tx] = ip[(size_t)(l0 + ty + i) * 512 + c0 + tx];
  __syncthreads();
  int p = threadIdx.x & 15;
  int lb = threadIdx.x >> 4;            // 0..15
#pragma unroll
  for (int i = 0; i < 2; ++i) {
    int ll = lb + i * 16;
    float v0 = tile[ll][2 * p];
    float v1 = tile[ll][2 * p + 1];
    unsigned short h0 = f2b(v0), h1 = f2b(v1);
    unsigned short q0 = f2b(v0 - b2f(h0)), q1 = f2b(v1 - b2f(h1));
    size_t o = ((size_t)b * 1024 + l0 + ll) * 256 + (c0 >> 1) + p;
    XPhi[o] = (unsigned)h0 | ((unsigned)h1 << 16);
    XPlo[o] = (unsigned)q0 | ((unsigned)q1 << 16);
  }
}

// ------- W split-repack: [1024 og][512 c][3 t] f32 ->
//         Wsp[(p*3+t)*1024 + og] uint2 {hi_pair, lo_pair}, p = c/2 -------
__global__ __launch_bounds__(256) void transpose_w_split(
    const float* __restrict__ Win, uint2* __restrict__ Wsp) {
  __shared__ float tile[32][49];        // [og][48 ct = 8 pairs x 3 t x 2]
  int og0 = blockIdx.x * 32;
  int ct0 = blockIdx.y * 48;
  int tid = threadIdx.x;
#pragma unroll
  for (int i = 0; i < 6; ++i) {
    int flat = tid + i * 256;
    int og = flat / 48, ct = flat % 48;
    tile[og][ct] = Win[(size_t)(og0 + og) * 1536 + ct0 + ct];
  }
  __syncthreads();
  int ogl = tid & 31;
  int s = tid >> 5;                     // 0..7
#pragma unroll
  for (int i = 0; i < 3; ++i) {
    int pt = s + i * 8;                 // 0..23
    int pl = pt / 3, t = pt % 3;
    float v0 = tile[ogl][pl * 6 + t];       // c = 2*(ct0/6 + pl)
    float v1 = tile[ogl][pl * 6 + 3 + t];   // c+1
    unsigned short h0 = f2b(v0), h1 = f2b(v1);
    unsigned short q0 = f2b(v0 - b2f(h0)), q1 = f2b(v1 - b2f(h1));
    Wsp[((size_t)(ct0 / 6 + pl) * 3 + t) * 1024 + og0 + ogl] =
        make_uint2((unsigned)h0 | ((unsigned)h1 << 16),
                   (unsigned)q0 | ((unsigned)q1 << 16));
  }
}

// ------- Conv1d(512->1024,k=3,pad=1) + GLU via MFMA v5 ------------------
// GEMM: C[og][l] = sum_{c,t} W[og][c][t] * X[c][l+t-1]; per block M=64 og,
// N=256 l (8 waves x 32), K=512c x 3t, 3-product hi/lo split. W tile in
// LDS (r4 staging, stride-18 rows); X B-fragments direct from L2. Per-wave
// acc 4x2 (32 AGPR) keeps unified regs ~108 -> 4 waves/SIMD (16 waves/CU).
// Grid 1024 = 16 b x 16 ca x 4 l, XCD-swizzled (each XCD owns 2 batches).
__global__ __launch_bounds__(512, 4) void conv_glu_mfma(
    const unsigned* __restrict__ XPhi, const unsigned* __restrict__ XPlo,
    const uint2* __restrict__ Wsp, const float* __restrict__ bias,
    float* __restrict__ q2t) {
  __shared__ unsigned Whi[3 * 64 * 18];
  __shared__ unsigned Wlo[3 * 64 * 18];

  int tid = threadIdx.x;
  int w = tid >> 6;                     // wave 0..7
  int lane = tid & 63;
  int grp = lane >> 4;                  // k-group 0..3
  int lid = lane & 15;

  unsigned v0 = blockIdx.x;             // 0..1023
  int xcd = (int)(v0 & 7u);
  int j = (int)(v0 >> 3);               // 0..127
  int b = xcd * 2 + (j >> 6);
  int rem = j & 63;
  int ca = (rem >> 2) * 32;             // GLU channel base
  int l0 = (rem & 3) * 256;             // l base

  const unsigned* xh = XPhi + (size_t)b * 1024 * 256;
  const unsigned* xl = XPlo + (size_t)b * 1024 * 256;

  int lbase = l0 + w * 32 + lid;        // + ni*16 + t - 1 per fragment

  f32x4 acc[4][2];
#pragma unroll
  for (int mi = 0; mi < 4; ++mi)
#pragma unroll
    for (int ni = 0; ni < 2; ++ni) acc[mi][ni] = {0.f, 0.f, 0.f, 0.f};

  for (int c0 = 0; c0 < 512; c0 += 32) {
    __syncthreads();
    // stage W tile: 16 pairs x 3 t x 64 og (a-rows 0..31, g-rows 32..63)
#pragma unroll
    for (int i = 0; i < 6; ++i) {
      int flat = tid + i * 512;
      int ogi = flat & 63;
      int r = flat >> 6;                // 0..47
      int t = r % 3, p = r / 3;
      int og = (ogi < 32) ? (ca + ogi) : (480 + ca + ogi);
      uint2 g = Wsp[((size_t)((c0 >> 1) + p) * 3 + t) * 1024 + og];
      Whi[(t * 64 + ogi) * 18 + p] = g.x;
      Wlo[(t * 64 + ogi) * 18 + p] = g.y;
    }
    __syncthreads();

#pragma unroll
    for (int t = 0; t < 3; ++t) {
      U8 Bh[2], Bl[2];
#pragma unroll
      for (int ni = 0; ni < 2; ++ni) {
        unsigned gl = (unsigned)(lbase + ni * 16 + t - 1);
        uint4 dh = make_uint4(0, 0, 0, 0), dl = make_uint4(0, 0, 0, 0);
        if (gl < 1024u) {
          size_t off = (size_t)gl * 256 + (c0 >> 1) + 4 * grp;
          dh = *(const uint4*)(xh + off);
          dl = *(const uint4*)(xl + off);
        }
        Bh[ni].u[0] = dh.x; Bh[ni].u[1] = dh.y;
        Bh[ni].u[2] = dh.z; Bh[ni].u[3] = dh.w;
        Bl[ni].u[0] = dl.x; Bl[ni].u[1] = dl.y;
        Bl[ni].u[2] = dl.z; Bl[ni].u[3] = dl.w;
      }
#pragma unroll
      for (int mi = 0; mi < 4; ++mi) {
        U8 Ah, Al;
        {
          int base = (t * 64 + mi * 16 + lid) * 18 + 4 * grp;
          uint2 h0 = *(const uint2*)&Whi[base];
          uint2 h1 = *(const uint2*)&Whi[base + 2];
          uint2 g0 = *(const uint2*)&Wlo[base];
          uint2 g1 = *(const uint2*)&Wlo[base + 2];
          Ah.u[0] = h0.x; Ah.u[1] = h0.y; Ah.u[2] = h1.x; Ah.u[3] = h1.y;
          Al.u[0] = g0.x; Al.u[1] = g0.y; Al.u[2] = g1.x; Al.u[3] = g1.y;
        }
#pragma unroll
        for (int ni = 0; ni < 2; ++ni) {
          acc[mi][ni] = __builtin_amdgcn_mfma_f32_16x16x32_bf16(
              Ah.v, Bl[ni].v, acc[mi][ni], 0, 0, 0);
          acc[mi][ni] = __builtin_amdgcn_mfma_f32_16x16x32_bf16(
              Al.v, Bh[ni].v, acc[mi][ni], 0, 0, 0);
          acc[mi][ni] = __builtin_amdgcn_mfma_f32_16x16x32_bf16(
              Ah.v, Bh[ni].v, acc[mi][ni], 0, 0, 0);
        }
      }
    }
  }

  // epilogue: GLU is lane-local (a at mi, g at mi+2, same lane)
#pragma unroll
  for (int mi = 0; mi < 2; ++mi)
#pragma unroll
    for (int rr = 0; rr < 4; ++rr) {
      int row = mi * 16 + grp * 4 + rr;     // 0..31
      float ba = bias[ca + row];
      float bg = bias[512 + ca + row];
      float* orow =
          q2t + ((size_t)b * 512 + ca + row) * 1024 + l0 + w * 32 + lid;
#pragma unroll
      for (int ni = 0; ni < 2; ++ni) {
        float a = acc[mi][ni][rr] + ba;
        float g = acc[mi + 2][ni][rr] + bg;
        orow[ni * 16] = a / (1.f + __expf(-g));
      }
    }
}

// ------- Forward rfft: f32 row [1024] -> 513 bf16-split complex ---------
__global__ __launch_bounds__(256) void fft_fwd_kernel(
    const float* __restrict__ in, ushort4* __restrict__ out, float scale) {
  __shared__ float2 sb0[1024];
  __shared__ float2 sb1[1024];
  __shared__ float2 twd[512];
  int tid = threadIdx.x;
  size_t r = blockIdx.x;                // row = (b*8+h)*64 + e
  const float* ip = in + r * 1024;
#pragma unroll
  for (int i = 0; i < 4; ++i) {
    int idx = tid + i * 256;
    sb0[idx] = make_float2(ip[idx], 0.f);
  }
  for (int kk = tid; kk < 512; kk += 256) {
    float ang = -6.283185307179586f * (float)kk * (1.0f / 1024.0f);
    float sn, cs;
    __sincosf(ang, &sn, &cs);
    twd[kk] = make_float2(cs, sn);
  }
  fft1024(sb0, sb1, twd, tid);
  ushort4* op = out + r * 514;          // padded row stride
  for (int x = tid; x < 513; x += 256) {
    float2 v = sb0[x];
    float re = v.x * scale, im = v.y * scale;
    unsigned short rh = f2b(re), ih = f2b(im);
    unsigned short rl = f2b(re - b2f(rh)), il = f2b(im - b2f(ih));
    op[x] = make_ushort4(rh, ih, rl, il);
  }
  if (tid == 0) op[513] = make_ushort4(0, 0, 0, 0);
}

// ------- vf transpose: [bh][64 e][514 y] uint2 -> vfT [bh][514 y][64 e] --
__global__ __launch_bounds__(256) void vft_kernel(
    const uint2* __restrict__ vf, uint2* __restrict__ vfT) {
  __shared__ uint2 tile[64][65];
  int bh = blockIdx.y;
  int y0 = blockIdx.x * 64;
  int tid = threadIdx.x;
  const uint2* src = vf + (size_t)bh * 64 * 514;
  uint2* dst = vfT + (size_t)bh * 514 * 64;
#pragma unroll
  for (int i = 0; i < 16; ++i) {
    int flat = tid + i * 256;
    int e = flat >> 6, y = flat & 63;
    int gy = y0 + y;
    uint2 d = make_uint2(0, 0);
    if (gy < 514) d = src[(size_t)e * 514 + gy];
    tile[e][y] = d;
  }
  __syncthreads();
#pragma unroll
  for (int i = 0; i < 16; ++i) {
    int flat = tid + i * 256;
    int y = flat >> 6, e = flat & 63;
    int gy = y0 + y;
    if (gy < 514) dst[(size_t)gy * 64 + e] = tile[e][y];
  }
}

// ---------------- Fused frequency attention v3 (MFMA, L2-direct K/V) -----
template <bool TAIL>
__device__ __forceinline__ void attn_tile(
    int y0, const uint2* __restrict__ kb, const uint2* __restrict__ vb,
    const U8 (&Ah)[2][4], const U8 (&Al)[2][4],
    unsigned* Shi, unsigned* Slo, float* zacc, f32x4* ore, f32x4* oim,
    int w, int grp, int lid) {
  int yk = y0 + 16 * w + lid;           // GEMM1 column owned by this lane
  uint2 BK[4][4];
  bool kval = !TAIL || (yk < 514);
#pragma unroll
  for (int ks = 0; ks < 4; ++ks)
#pragma unroll
    for (int jp = 0; jp < 4; ++jp) {
      int e = ks * 16 + grp * 4 + jp;
      if (!TAIL) {
        BK[ks][jp] = kb[(size_t)e * 514 + yk];
      } else {
        uint2 d = make_uint2(0, 0);
        if (kval) d = kb[(size_t)e * 514 + yk];
        BK[ks][jp] = d;
      }
    }
  f32x4 cre[2] = {{0.f, 0.f, 0.f, 0.f}, {0.f, 0.f, 0.f, 0.f}};
  f32x4 cim[2] = {{0.f, 0.f, 0.f, 0.f}, {0.f, 0.f, 0.f, 0.f}};
#pragma unroll
  for (int ks = 0; ks < 4; ++ks) {
    U8 bhh, bll, bih, bil;
#pragma unroll
    for (int jp = 0; jp < 4; ++jp) {
      unsigned uh = BK[ks][jp].x, ul = BK[ks][jp].y;
      bhh.u[jp] = uh;                                  // (kr, ki)
      bll.u[jp] = ul;
      bih.u[jp] = ((uh >> 16) ^ 0x8000u) | (uh << 16); // (-ki, kr)
      bil.u[jp] = ((ul >> 16) ^ 0x8000u) | (ul << 16);
    }
#pragma unroll
    for (int mt = 0; mt < 2; ++mt) {
      cre[mt] = __builtin_amdgcn_mfma_f32_16x16x32_bf16(Ah[mt][ks].v, bhh.v, cre[mt], 0, 0, 0);
      cre[mt] = __builtin_amdgcn_mfma_f32_16x16x32_bf16(Al[mt][ks].v, bhh.v, cre[mt], 0, 0, 0);
      cre[mt] = __builtin_amdgcn_mfma_f32_16x16x32_bf16(Ah[mt][ks].v, bll.v, cre[mt], 0, 0, 0);
      cim[mt] = __builtin_amdgcn_mfma_f32_16x16x32_bf16(Ah[mt][ks].v, bih.v, cim[mt], 0, 0, 0);
      cim[mt] = __builtin_amdgcn_mfma_f32_16x16x32_bf16(Al[mt][ks].v, bih.v, cim[mt], 0, 0, 0);
      cim[mt] = __builtin_amdgcn_mfma_f32_16x16x32_bf16(Ah[mt][ks].v, bil.v, cim[mt], 0, 0, 0);
    }
  }
  // ---- gate + L1 partial + split scores to LDS ----
#pragma unroll
  for (int mt = 0; mt < 2; ++mt)
#pragma unroll
    for (int r = 0; r < 4; ++r) {
      float sre = cre[mt][r], sim = cim[mt][r];
      float m = sqrtf(sre * sre + sim * sim);
      float f = 1.f + 1.f / (1.f + __expf(-m));
      zacc[mt * 4 + r] += m * f;
      float wre = sre * f, wim = sim * f;
      unsigned dh = cvtpk_bf16(wre, wim);
      float rre = wre - __uint_as_float(dh << 16);
      float rim = wim - __uint_as_float(dh & 0xffff0000u);
      unsigned dl = cvtpk_bf16(rre, rim);
      int x = mt * 16 + grp * 4 + r;
      int idx = x * 64 + ((16 * w + lid) ^ ((x & 15) << 2));
      Shi[idx] = dh;
      Slo[idx] = dl;
    }
  __syncthreads();
  // ---- GEMM2: of[x][e] += sc * vf ----
#pragma unroll
  for (int ks = 0; ks < 4; ++ks) {
    uint2 BV[4];
#pragma unroll
    for (int jp = 0; jp < 4; ++jp) {
      int yv = y0 + ks * 16 + grp * 4 + jp;
      if (!TAIL) {
        BV[jp] = vb[(size_t)yv * 64 + 16 * w + lid];
      } else {
        uint2 d = make_uint2(0, 0);
        if (yv < 514) d = vb[(size_t)yv * 64 + 16 * w + lid];
        BV[jp] = d;
      }
    }
    U8 bvh, bvl, bvi, bvj;
#pragma unroll
    for (int jp = 0; jp < 4; ++jp) {
      unsigned uh = BV[jp].x, ul = BV[jp].y;
      bvh.u[jp] = uh ^ 0x80000000u;            // (vr, -vi)
      bvl.u[jp] = ul ^ 0x80000000u;
      bvi.u[jp] = (uh >> 16) | (uh << 16);     // (vi, vr)
      bvj.u[jp] = (ul >> 16) | (ul << 16);
    }
#pragma unroll
    for (int mt = 0; mt < 2; ++mt) {
      int sidx = (mt * 16 + lid) * 64 + ((ks * 16 + grp * 4) ^ (lid << 2));
      U8 a2h, a2l;
      a2h.v = *(const bf16x8*)&Shi[sidx];
      a2l.v = *(const bf16x8*)&Slo[sidx];
      ore[mt] = __builtin_amdgcn_mfma_f32_16x16x32_bf16(a2h.v, bvh.v, ore[mt], 0, 0, 0);
      ore[mt] = __builtin_amdgcn_mfma_f32_16x16x32_bf16(a2l.v, bvh.v, ore[mt], 0, 0, 0);
      ore[mt] = __builtin_amdgcn_mfma_f32_16x16x32_bf16(a2h.v, bvl.v, ore[mt], 0, 0, 0);
      oim[mt] = __builtin_amdgcn_mfma_f32_16x16x32_bf16(a2h.v, bvi.v, oim[mt], 0, 0, 0);
      oim[mt] = __builtin_amdgcn_mfma_f32_16x16x32_bf16(a2l.v, bvi.v, oim[mt], 0, 0, 0);
      oim[mt] = __builtin_amdgcn_mfma_f32_16x16x32_bf16(a2h.v, bvj.v, oim[mt], 0, 0, 0);
    }
  }
  __syncthreads();                      // before next tile's S overwrite
}

__global__ __launch_bounds__(256, 3) void attn_kernel(
    const uint2* __restrict__ qf, const uint2* __restrict__ kf,
    const uint2* __restrict__ vfT, float2* __restrict__ of) {
  __shared__ __align__(16) unsigned char smem[16896];
  unsigned* Shi = (unsigned*)smem;              // [32 x][64 y] dw, swizzled
  unsigned* Slo = (unsigned*)(smem + 8192);
  float* zred = (float*)(smem + 16384);         // [4 w][32 x]

  int tid = threadIdx.x;
  int w = tid >> 6;                             // wave 0..3
  int lane = tid & 63;
  int grp = lane >> 4;                          // k-group 0..3
  int lid = lane & 15;

  unsigned v0 = blockIdx.x;                     // 0..2175
  unsigned cc = v0 & 7u;                        // XCD
  unsigned jj = v0 >> 3;                        // 0..271
  int bh = (int)(cc + 8u * (jj / 17u));
  int x0 = (int)(jj % 17u) * 32;

  const uint2* qb = qf + (size_t)bh * (64 * 514);
  const uint2* kb = kf + (size_t)bh * (64 * 514);
  const uint2* vb = vfT + (size_t)bh * (514 * 64);

  // ---- A fragments (q) direct from global (coalesced per quarter) ----
  U8 Ah[2][4], Al[2][4];
#pragma unroll
  for (int mt = 0; mt < 2; ++mt) {
    int gx = x0 + mt * 16 + lid;
    bool qv = gx < 514;
#pragma unroll
    for (int ks = 0; ks < 4; ++ks)
#pragma unroll
      for (int jp = 0; jp < 4; ++jp) {
        int e = ks * 16 + grp * 4 + jp;
        uint2 d = make_uint2(0, 0);
        if (qv) d = qb[(size_t)e * 514 + gx];
        Ah[mt][ks].u[jp] = d.x;
        Al[mt][ks].u[jp] = d.y;
      }
  }

  float zacc[8] = {0.f, 0.f, 0.f, 0.f, 0.f, 0.f, 0.f, 0.f};
  f32x4 ore[2] = {{0.f, 0.f, 0.f, 0.f}, {0.f, 0.f, 0.f, 0.f}};
  f32x4 oim[2] = {{0.f, 0.f, 0.f, 0.f}, {0.f, 0.f, 0.f, 0.f}};

#pragma unroll 1
  for (int yt = 0; yt < 8; ++yt)
    attn_tile<false>(yt * 64, kb, vb, Ah, Al, Shi, Slo, zacc, ore, oim,
                     w, grp, lid);
  attn_tile<true>(512, kb, vb, Ah, Al, Shi, Slo, zacc, ore, oim,
                  w, grp, lid);

  // ---- Z reduction: per-lane partials -> per-x totals ----
#pragma unroll
  for (int mt = 0; mt < 2; ++mt)
#pragma unroll
    for (int r = 0; r < 4; ++r) {
      float z = zacc[mt * 4 + r];
      z += __shfl_xor(z, 1); z += __shfl_xor(z, 2);
      z += __shfl_xor(z, 4); z += __shfl_xor(z, 8);
      zacc[mt * 4 + r] = z;
    }
  if (lid == 0) {
#pragma unroll
    for (int mt = 0; mt < 2; ++mt)
#pragma unroll
      for (int r = 0; r < 4; ++r)
        zred[w * 32 + mt * 16 + grp * 4 + r] = zacc[mt * 4 + r];
  }
  __syncthreads();
  // ---- normalize + stage output tile [64 e][32 x] (swz x ^ ((e&7)<<2)) ----
  float2* ov = (float2*)smem;           // aliases S planes (16 KB)
#pragma unroll
  for (int mt = 0; mt < 2; ++mt)
#pragma unroll
    for (int r = 0; r < 4; ++r) {
      int x = mt * 16 + grp * 4 + r;
      float z = zred[x] + zred[32 + x] + zred[64 + x] + zred[96 + x];
      float inv = 1.f / fmaxf(z, 1e-12f);
      int e = w * 16 + lid;
      ov[e * 32 + (x ^ ((e & 7) << 2))] =
          make_float2(ore[mt][r] * inv, oim[mt][r] * inv);
    }
  __syncthreads();
  // ---- coalesced write: of[(bh*64+e)*513 + x] ----
  {
    float2* ob = of + (size_t)bh * 64 * 513;
#pragma unroll
    for (int i = 0; i < 4; ++i) {
      int e = (tid >> 4) + i * 16;
      int xq = (tid & 15) * 2;
      int sw = (e & 7) << 2;
      float2 a = ov[e * 32 + (xq ^ sw)];
      float2 b2 = ov[e * 32 + ((xq + 1) ^ sw)];
      int gx = x0 + xq;
      if (gx < 513) ob[(size_t)e * 513 + gx] = a;
      if (gx + 1 < 513) ob[(size_t)e * 513 + gx + 1] = b2;
    }
  }
}

// ------- Inverse rfft (ortho), of stride 513 -> f32 out [B,L,H,E] -------
__global__ __launch_bounds__(256) void fft_inv_kernel(
    const float2* __restrict__ in, float* __restrict__ out) {
  __shared__ float2 sb0[1024];
  __shared__ float2 sb1[1024];
  __shared__ float2 twd[512];
  int tid = threadIdx.x;
  size_t r = blockIdx.x;                // (b*8+h)*64 + e
  const float2* ip = in + r * 513;
#pragma unroll
  for (int i = 0; i < 4; ++i) {
    int idx = tid + i * 256;
    float2 v;
    if (idx < 513) {
      v = ip[idx];
    } else {                            // Hermitian mirror
      float2 u = ip[1024 - idx];
      v = make_float2(u.x, -u.y);
    }
    sb0[idx] = v;
  }
  for (int kk = tid; kk < 512; kk += 256) {
    float ang = 6.283185307179586f * (float)kk * (1.0f / 1024.0f);
    float sn, cs;
    __sincosf(ang, &sn, &cs);
    twd[kk] = make_float2(cs, sn);
  }
  fft1024(sb0, sb1, twd, tid);
  int e = (int)(r & 63);
  int h = (int)((r >> 6) & 7);
  size_t b = r >> 9;
  float* op = out + b * (size_t)(1024 * 512) + (size_t)h * 64 + e;
  const float sc = 0.03125f;            // 1/sqrt(1024)
#pragma unroll
  for (int i = 0; i < 4; ++i) {
    int l = tid + i * 256;
    op[(size_t)l * 512] = sb0[l].x * sc;
  }
}

// ---------------- launch ------------------------------------------------
extern "C" void kernel_launch(void* const* d_in, const int* in_sizes, int n_in,
                              void* d_out, int out_size, void* d_ws, size_t ws_size,
                              hipStream_t stream) {
  const float* q = (const float*)d_in[0];
  const float* k = (const float*)d_in[1];
  const float* v = (const float*)d_in[2];
  const float* W = (const float*)d_in[3];
  const float* bias = (const float*)d_in[4];
  float* out = (float*)d_out;

  // Workspace map (float offsets), regions of 8,421,376 floats each:
  //   A   [0)         reused: q2t -> kT -> vT -> vfT
  //   QFR [8421376)   reused: XPhi+XPlo (split q) -> qf (bf16-split freq)
  //   R2  [16842752)  reused: Wsp (split W) -> vf -> of
  //   R3  [25264128)  kf
  float* wsf = (float*)d_ws;
  float*    A    = wsf;
  uint2*    vfT  = (uint2*)wsf;
  unsigned* XPhi = (unsigned*)(wsf + 8421376);
  unsigned* XPlo = XPhi + (size_t)16 * 1024 * 256;   // +16 MB
  ushort4*  qf   = (ushort4*)(wsf + 8421376);
  uint2*    Wsp  = (uint2*)(wsf + 16842752);
  ushort4*  vf   = (ushort4*)(wsf + 16842752);
  float2*   of   = (float2*)(wsf + 16842752);        // overwrites vf
  ushort4*  kf   = (ushort4*)(wsf + 25264128);

  transpose_q_split<<<dim3(32, 16, 16), 256, 0, stream>>>(q, XPhi, XPlo);
  transpose_w_split<<<dim3(32, 32), 256, 0, stream>>>(W, Wsp);
  conv_glu_mfma<<<dim3(1024), 512, 0, stream>>>(XPhi, XPlo, Wsp, bias, A);
  fft_fwd_kernel<<<dim3(8192), 256, 0, stream>>>(A, qf, 0.03125f * 0.125f);
  transpose_kernel<<<dim3(32, 16, 16), 256, 0, stream>>>(k, A);
  fft_fwd_kernel<<<dim3(8192), 256, 0, stream>>>(A, kf, 0.03125f);
  transpose_kernel<<<dim3(32, 16, 16), 256, 0, stream>>>(v, A);
  fft_fwd_kernel<<<dim3(8192), 256, 0, stream>>>(A, vf, 0.03125f);
  vft_kernel<<<dim3(9, 128), 256, 0, stream>>>((const uint2*)vf, vfT);
  attn_kernel<<<dim3(2176), 256, 0, stream>>>((const uint2*)qf, (const uint2*)kf,
                                              vfT, of);
  fft_inv_kernel<<<dim3(8192), 256, 0, stream>>>(of, out);
}

// Round 11
// 715.619 us; speedup vs baseline: 1.2489x; 1.0663x over previous
//
#include <hip/hip_runtime.h>
#include <math.h>

// Problem: B=16, L=S=1024, H=8, E=64, d=512, Lf=513 (freq rows PADDED to 514)
// Pipeline: split-transpose(q) -> split-repack(W) -> conv+GLU (MFMA v5,
//           8-wave blocks) -> rfft2(q2) -> transpose(k) -> rfft2 ->
//           transpose(v) -> rfft2 -> vf-transpose -> attn(MFMA, L2-direct K/V)
//           -> irfft2
// All matmul-shaped compute runs on mfma_f32_16x16x32_bf16 with a 3-product
// error-compensated hi/lo split (~2^-17 per product; below f32-FFT floor).
// FFT v2c: TWO real rows per complex 1024-pt FFT (z = x+iy; Hermitian
// unpack/pack). r9/r10 LESSON: irfft IGNORES Im(DC) and Im(Nyquist); the
// packed inverse must ZERO bins 0/512's imag parts before packing, else
// each row's DC/Nyquist imag (O(1) in attn output) contaminates its pair
// partner at ~|b|/32 ~ 6e-3 (the exact observed failure).
// conv v5 (r8): 64og x 256l block, W in LDS, 512-thread/8-wave blocks,
// acc 4x2 -> 64 VGPR, occupancy 42%, 237 us (best known).
// Workspace: 4 regions x 8,421,376 floats = 134,742,016 bytes.

typedef __attribute__((ext_vector_type(8))) short bf16x8;
typedef __attribute__((ext_vector_type(4))) float f32x4;

union U8 { bf16x8 v; unsigned u[4]; };

__device__ __forceinline__ unsigned short f2b(float x) {  // f32 -> bf16 RNE
  unsigned u = __float_as_uint(x);
  return (unsigned short)((u + 0x7FFFu + ((u >> 16) & 1u)) >> 16);
}
__device__ __forceinline__ float b2f(unsigned short h) {
  return __uint_as_float(((unsigned)h) << 16);
}
__device__ __forceinline__ unsigned cvtpk_bf16(float lo, float hi) {
  unsigned r;  // dst.lo16 = bf16(lo), dst.hi16 = bf16(hi)
  asm("v_cvt_pk_bf16_f32 %0, %1, %2" : "=v"(r) : "v"(lo), "v"(hi));
  return r;
}

// ---------------- Stockham FFT core, N=1024, 256 threads ----------------
__device__ __forceinline__ void fft1024(float2* b0, float2* b1,
                                        const float2* twd, int tid) {
  float2* src = b0;
  float2* dst = b1;
#pragma unroll
  for (int st = 0; st < 10; ++st) {
    __syncthreads();
#pragma unroll
    for (int qq = 0; qq < 2; ++qq) {
      int bi = tid + qq * 256;          // butterfly index in [0,512)
      int m = 1 << st;
      int j = bi >> st;
      int jm = j << st;
      float2 c0 = src[bi];
      float2 c1 = src[bi + 512];
      float2 w = twd[jm];
      float2 sum, dif, tw;
      sum.x = c0.x + c1.x; sum.y = c0.y + c1.y;
      dif.x = c0.x - c1.x; dif.y = c0.y - c1.y;
      tw.x = dif.x * w.x - dif.y * w.y;
      tw.y = dif.x * w.y + dif.y * w.x;
      dst[bi + jm] = sum;
      dst[bi + jm + m] = tw;
    }
    float2* tmp = src; src = dst; dst = tmp;
  }
  __syncthreads();
}

// ---------------- transpose: f32 [B][1024][512] -> f32 [B][512][1024] ---
__global__ __launch_bounds__(256) void transpose_kernel(
    const float* __restrict__ in, float* __restrict__ out) {
  __shared__ float tile[32][33];
  int b = blockIdx.z;
  int s0 = blockIdx.x * 32;
  int c0 = blockIdx.y * 32;
  int tx = threadIdx.x & 31;
  int ty = threadIdx.x >> 5;            // 0..7
  const float* ip = in + (size_t)b * (1024 * 512);
  float* op = out + (size_t)b * (1024 * 512);
#pragma unroll
  for (int i = 0; i < 32; i += 8)
    tile[ty + i][tx] = ip[(size_t)(s0 + ty + i) * 512 + c0 + tx];
  __syncthreads();
#pragma unroll
  for (int i = 0; i < 32; i += 8)
    op[(size_t)(c0 + ty + i) * 1024 + s0 + tx] = tile[tx][ty + i];
}

// ------- q split-transpose: f32 [B][1024 l][512 c] -> bf16-split pair ---
__global__ __launch_bounds__(256) void transpose_q_split(
    const float* __restrict__ in, unsigned* __restrict__ XPhi,
    unsigned* __restrict__ XPlo) {
  __shared__ float tile[32][33];
  int b = blockIdx.z;
  int l0 = blockIdx.x * 32;
  int c0 = blockIdx.y * 32;
  int tx = threadIdx.x & 31;
  int ty = threadIdx.x >> 5;            // 0..7
  const float* ip = in + (size_t)b * (1024 * 512);
#pragma unroll
  for (int i = 0; i < 32; i += 8)
    tile[ty + i][tx] = ip[(size_t)(l0 + ty + i) * 512 + c0 + tx];
  __syncthreads();
  int p = threadIdx.x & 15;
  int lb = threadIdx.x >> 4;            // 0..15
#pragma unroll
  for (int i = 0; i < 2; ++i) {
    int ll = lb + i * 16;
    float v0 = tile[ll][2 * p];
    float v1 = tile[ll][2 * p + 1];
    unsigned short h0 = f2b(v0), h1 = f2b(v1);
    unsigned short q0 = f2b(v0 - b2f(h0)), q1 = f2b(v1 - b2f(h1));
    size_t o = ((size_t)b * 1024 + l0 + ll) * 256 + (c0 >> 1) + p;
    XPhi[o] = (unsigned)h0 | ((unsigned)h1 << 16);
    XPlo[o] = (unsigned)q0 | ((unsigned)q1 << 16);
  }
}

// ------- W split-repack: [1024 og][512 c][3 t] f32 ->
//         Wsp[(p*3+t)*1024 + og] uint2 {hi_pair, lo_pair}, p = c/2 -------
__global__ __launch_bounds__(256) void transpose_w_split(
    const float* __restrict__ Win, uint2* __restrict__ Wsp) {
  __shared__ float tile[32][49];        // [og][48 ct = 8 pairs x 3 t x 2]
  int og0 = blockIdx.x * 32;
  int ct0 = blockIdx.y * 48;
  int tid = threadIdx.x;
#pragma unroll
  for (int i = 0; i < 6; ++i) {
    int flat = tid + i * 256;
    int og = flat / 48, ct = flat % 48;
    tile[og][ct] = Win[(size_t)(og0 + og) * 1536 + ct0 + ct];
  }
  __syncthreads();
  int ogl = tid & 31;
  int s = tid >> 5;                     // 0..7
#pragma unroll
  for (int i = 0; i < 3; ++i) {
    int pt = s + i * 8;                 // 0..23
    int pl = pt / 3, t = pt % 3;
    float v0 = tile[ogl][pl * 6 + t];       // c = 2*(ct0/6 + pl)
    float v1 = tile[ogl][pl * 6 + 3 + t];   // c+1
    unsigned short h0 = f2b(v0), h1 = f2b(v1);
    unsigned short q0 = f2b(v0 - b2f(h0)), q1 = f2b(v1 - b2f(h1));
    Wsp[((size_t)(ct0 / 6 + pl) * 3 + t) * 1024 + og0 + ogl] =
        make_uint2((unsigned)h0 | ((unsigned)h1 << 16),
                   (unsigned)q0 | ((unsigned)q1 << 16));
  }
}

// ------- Conv1d(512->1024,k=3,pad=1) + GLU via MFMA v5 ------------------
__global__ __launch_bounds__(512, 4) void conv_glu_mfma(
    const unsigned* __restrict__ XPhi, const unsigned* __restrict__ XPlo,
    const uint2* __restrict__ Wsp, const float* __restrict__ bias,
    float* __restrict__ q2t) {
  __shared__ unsigned Whi[3 * 64 * 18];
  __shared__ unsigned Wlo[3 * 64 * 18];

  int tid = threadIdx.x;
  int w = tid >> 6;                     // wave 0..7
  int lane = tid & 63;
  int grp = lane >> 4;                  // k-group 0..3
  int lid = lane & 15;

  unsigned v0 = blockIdx.x;             // 0..1023
  int xcd = (int)(v0 & 7u);
  int j = (int)(v0 >> 3);               // 0..127
  int b = xcd * 2 + (j >> 6);
  int rem = j & 63;
  int ca = (rem >> 2) * 32;             // GLU channel base
  int l0 = (rem & 3) * 256;             // l base

  const unsigned* xh = XPhi + (size_t)b * 1024 * 256;
  const unsigned* xl = XPlo + (size_t)b * 1024 * 256;

  int lbase = l0 + w * 32 + lid;        // + ni*16 + t - 1 per fragment

  f32x4 acc[4][2];
#pragma unroll
  for (int mi = 0; mi < 4; ++mi)
#pragma unroll
    for (int ni = 0; ni < 2; ++ni) acc[mi][ni] = {0.f, 0.f, 0.f, 0.f};

  for (int c0 = 0; c0 < 512; c0 += 32) {
    __syncthreads();
    // stage W tile: 16 pairs x 3 t x 64 og (a-rows 0..31, g-rows 32..63)
#pragma unroll
    for (int i = 0; i < 6; ++i) {
      int flat = tid + i * 512;
      int ogi = flat & 63;
      int r = flat >> 6;                // 0..47
      int t = r % 3, p = r / 3;
      int og = (ogi < 32) ? (ca + ogi) : (480 + ca + ogi);
      uint2 g = Wsp[((size_t)((c0 >> 1) + p) * 3 + t) * 1024 + og];
      Whi[(t * 64 + ogi) * 18 + p] = g.x;
      Wlo[(t * 64 + ogi) * 18 + p] = g.y;
    }
    __syncthreads();

#pragma unroll
    for (int t = 0; t < 3; ++t) {
      U8 Bh[2], Bl[2];
#pragma unroll
      for (int ni = 0; ni < 2; ++ni) {
        unsigned gl = (unsigned)(lbase + ni * 16 + t - 1);
        uint4 dh = make_uint4(0, 0, 0, 0), dl = make_uint4(0, 0, 0, 0);
        if (gl < 1024u) {
          size_t off = (size_t)gl * 256 + (c0 >> 1) + 4 * grp;
          dh = *(const uint4*)(xh + off);
          dl = *(const uint4*)(xl + off);
        }
        Bh[ni].u[0] = dh.x; Bh[ni].u[1] = dh.y;
        Bh[ni].u[2] = dh.z; Bh[ni].u[3] = dh.w;
        Bl[ni].u[0] = dl.x; Bl[ni].u[1] = dl.y;
        Bl[ni].u[2] = dl.z; Bl[ni].u[3] = dl.w;
      }
#pragma unroll
      for (int mi = 0; mi < 4; ++mi) {
        U8 Ah, Al;
        {
          int base = (t * 64 + mi * 16 + lid) * 18 + 4 * grp;
          uint2 h0 = *(const uint2*)&Whi[base];
          uint2 h1 = *(const uint2*)&Whi[base + 2];
          uint2 g0 = *(const uint2*)&Wlo[base];
          uint2 g1 = *(const uint2*)&Wlo[base + 2];
          Ah.u[0] = h0.x; Ah.u[1] = h0.y; Ah.u[2] = h1.x; Ah.u[3] = h1.y;
          Al.u[0] = g0.x; Al.u[1] = g0.y; Al.u[2] = g1.x; Al.u[3] = g1.y;
        }
#pragma unroll
        for (int ni = 0; ni < 2; ++ni) {
          acc[mi][ni] = __builtin_amdgcn_mfma_f32_16x16x32_bf16(
              Ah.v, Bl[ni].v, acc[mi][ni], 0, 0, 0);
          acc[mi][ni] = __builtin_amdgcn_mfma_f32_16x16x32_bf16(
              Al.v, Bh[ni].v, acc[mi][ni], 0, 0, 0);
          acc[mi][ni] = __builtin_amdgcn_mfma_f32_16x16x32_bf16(
              Ah.v, Bh[ni].v, acc[mi][ni], 0, 0, 0);
        }
      }
    }
  }

  // epilogue: GLU is lane-local (a at mi, g at mi+2, same lane)
#pragma unroll
  for (int mi = 0; mi < 2; ++mi)
#pragma unroll
    for (int rr = 0; rr < 4; ++rr) {
      int row = mi * 16 + grp * 4 + rr;     // 0..31
      float ba = bias[ca + row];
      float bg = bias[512 + ca + row];
      float* orow =
          q2t + ((size_t)b * 512 + ca + row) * 1024 + l0 + w * 32 + lid;
#pragma unroll
      for (int ni = 0; ni < 2; ++ni) {
        float a = acc[mi][ni][rr] + ba;
        float g = acc[mi + 2][ni][rr] + bg;
        orow[ni * 16] = a / (1.f + __expf(-g));
      }
    }
}

// ------- Forward rfft x2: two real rows per complex FFT -----------------
// rows r0=2*bid, r0+1; z = x + iy; X=(Z_k+conj(Z_{N-k}))/2,
// Y=-i(Z_k-conj(Z_{N-k}))/2. Out: bf16-split ushort4, stride 514, col 513=0.
// (At bins 0/512, Zn==Zk so imag parts are exactly 0 -- matches rfft.)
__global__ __launch_bounds__(256) void fft_fwd2_kernel(
    const float* __restrict__ in, ushort4* __restrict__ out, float scale) {
  __shared__ float2 sb0[1024];
  __shared__ float2 sb1[1024];
  __shared__ float2 twd[512];
  int tid = threadIdx.x;
  size_t r0 = (size_t)blockIdx.x * 2;
  const float* ip0 = in + r0 * 1024;
  const float* ip1 = ip0 + 1024;
#pragma unroll
  for (int i = 0; i < 4; ++i) {
    int idx = tid + i * 256;
    sb0[idx] = make_float2(ip0[idx], ip1[idx]);
  }
  for (int kk = tid; kk < 512; kk += 256) {
    float ang = -6.283185307179586f * (float)kk * (1.0f / 1024.0f);
    float sn, cs;
    __sincosf(ang, &sn, &cs);
    twd[kk] = make_float2(cs, sn);
  }
  fft1024(sb0, sb1, twd, tid);
  ushort4* op0 = out + r0 * 514;        // padded row stride
  ushort4* op1 = op0 + 514;
  float sc = 0.5f * scale;              // unpack 1/2 folded into scale
  for (int x = tid; x < 513; x += 256) {
    float2 Zk = sb0[x];
    float2 Zn = sb0[(1024 - x) & 1023];
    float xre = (Zk.x + Zn.x) * sc, xim = (Zk.y - Zn.y) * sc;
    float yre = (Zk.y + Zn.y) * sc, yim = (Zn.x - Zk.x) * sc;
    unsigned short rh = f2b(xre), ih = f2b(xim);
    unsigned short rl = f2b(xre - b2f(rh)), il = f2b(xim - b2f(ih));
    op0[x] = make_ushort4(rh, ih, rl, il);
    rh = f2b(yre); ih = f2b(yim);
    rl = f2b(yre - b2f(rh)); il = f2b(yim - b2f(ih));
    op1[x] = make_ushort4(rh, ih, rl, il);
  }
  if (tid == 0) {
    op0[513] = make_ushort4(0, 0, 0, 0);
    op1[513] = make_ushort4(0, 0, 0, 0);
  }
}

// ------- vf transpose: [bh][64 e][514 y] uint2 -> vfT [bh][514 y][64 e] --
__global__ __launch_bounds__(256) void vft_kernel(
    const uint2* __restrict__ vf, uint2* __restrict__ vfT) {
  __shared__ uint2 tile[64][65];
  int bh = blockIdx.y;
  int y0 = blockIdx.x * 64;
  int tid = threadIdx.x;
  const uint2* src = vf + (size_t)bh * 64 * 514;
  uint2* dst = vfT + (size_t)bh * 514 * 64;
#pragma unroll
  for (int i = 0; i < 16; ++i) {
    int flat = tid + i * 256;
    int e = flat >> 6, y = flat & 63;
    int gy = y0 + y;
    uint2 d = make_uint2(0, 0);
    if (gy < 514) d = src[(size_t)e * 514 + gy];
    tile[e][y] = d;
  }
  __syncthreads();
#pragma unroll
  for (int i = 0; i < 16; ++i) {
    int flat = tid + i * 256;
    int y = flat >> 6, e = flat & 63;
    int gy = y0 + y;
    if (gy < 514) dst[(size_t)gy * 64 + e] = tile[e][y];
  }
}

// ---------------- Fused frequency attention v3 (MFMA, L2-direct K/V) -----
template <bool TAIL>
__device__ __forceinline__ void attn_tile(
    int y0, const uint2* __restrict__ kb, const uint2* __restrict__ vb,
    const U8 (&Ah)[2][4], const U8 (&Al)[2][4],
    unsigned* Shi, unsigned* Slo, float* zacc, f32x4* ore, f32x4* oim,
    int w, int grp, int lid) {
  int yk = y0 + 16 * w + lid;           // GEMM1 column owned by this lane
  uint2 BK[4][4];
  bool kval = !TAIL || (yk < 514);
#pragma unroll
  for (int ks = 0; ks < 4; ++ks)
#pragma unroll
    for (int jp = 0; jp < 4; ++jp) {
      int e = ks * 16 + grp * 4 + jp;
      if (!TAIL) {
        BK[ks][jp] = kb[(size_t)e * 514 + yk];
      } else {
        uint2 d = make_uint2(0, 0);
        if (kval) d = kb[(size_t)e * 514 + yk];
        BK[ks][jp] = d;
      }
    }
  f32x4 cre[2] = {{0.f, 0.f, 0.f, 0.f}, {0.f, 0.f, 0.f, 0.f}};
  f32x4 cim[2] = {{0.f, 0.f, 0.f, 0.f}, {0.f, 0.f, 0.f, 0.f}};
#pragma unroll
  for (int ks = 0; ks < 4; ++ks) {
    U8 bhh, bll, bih, bil;
#pragma unroll
    for (int jp = 0; jp < 4; ++jp) {
      unsigned uh = BK[ks][jp].x, ul = BK[ks][jp].y;
      bhh.u[jp] = uh;                                  // (kr, ki)
      bll.u[jp] = ul;
      bih.u[jp] = ((uh >> 16) ^ 0x8000u) | (uh << 16); // (-ki, kr)
      bil.u[jp] = ((ul >> 16) ^ 0x8000u) | (ul << 16);
    }
#pragma unroll
    for (int mt = 0; mt < 2; ++mt) {
      cre[mt] = __builtin_amdgcn_mfma_f32_16x16x32_bf16(Ah[mt][ks].v, bhh.v, cre[mt], 0, 0, 0);
      cre[mt] = __builtin_amdgcn_mfma_f32_16x16x32_bf16(Al[mt][ks].v, bhh.v, cre[mt], 0, 0, 0);
      cre[mt] = __builtin_amdgcn_mfma_f32_16x16x32_bf16(Ah[mt][ks].v, bll.v, cre[mt], 0, 0, 0);
      cim[mt] = __builtin_amdgcn_mfma_f32_16x16x32_bf16(Ah[mt][ks].v, bih.v, cim[mt], 0, 0, 0);
      cim[mt] = __builtin_amdgcn_mfma_f32_16x16x32_bf16(Al[mt][ks].v, bih.v, cim[mt], 0, 0, 0);
      cim[mt] = __builtin_amdgcn_mfma_f32_16x16x32_bf16(Ah[mt][ks].v, bil.v, cim[mt], 0, 0, 0);
    }
  }
  // ---- gate + L1 partial + split scores to LDS ----
#pragma unroll
  for (int mt = 0; mt < 2; ++mt)
#pragma unroll
    for (int r = 0; r < 4; ++r) {
      float sre = cre[mt][r], sim = cim[mt][r];
      float m = sqrtf(sre * sre + sim * sim);
      float f = 1.f + 1.f / (1.f + __expf(-m));
      zacc[mt * 4 + r] += m * f;
      float wre = sre * f, wim = sim * f;
      unsigned dh = cvtpk_bf16(wre, wim);
      float rre = wre - __uint_as_float(dh << 16);
      float rim = wim - __uint_as_float(dh & 0xffff0000u);
      unsigned dl = cvtpk_bf16(rre, rim);
      int x = mt * 16 + grp * 4 + r;
      int idx = x * 64 + ((16 * w + lid) ^ ((x & 15) << 2));
      Shi[idx] = dh;
      Slo[idx] = dl;
    }
  __syncthreads();
  // ---- GEMM2: of[x][e] += sc * vf ----
#pragma unroll
  for (int ks = 0; ks < 4; ++ks) {
    uint2 BV[4];
#pragma unroll
    for (int jp = 0; jp < 4; ++jp) {
      int yv = y0 + ks * 16 + grp * 4 + jp;
      if (!TAIL) {
        BV[jp] = vb[(size_t)yv * 64 + 16 * w + lid];
      } else {
        uint2 d = make_uint2(0, 0);
        if (yv < 514) d = vb[(size_t)yv * 64 + 16 * w + lid];
        BV[jp] = d;
      }
    }
    U8 bvh, bvl, bvi, bvj;
#pragma unroll
    for (int jp = 0; jp < 4; ++jp) {
      unsigned uh = BV[jp].x, ul = BV[jp].y;
      bvh.u[jp] = uh ^ 0x80000000u;            // (vr, -vi)
      bvl.u[jp] = ul ^ 0x80000000u;
      bvi.u[jp] = (uh >> 16) | (uh << 16);     // (vi, vr)
      bvj.u[jp] = (ul >> 16) | (ul << 16);
    }
#pragma unroll
    for (int mt = 0; mt < 2; ++mt) {
      int sidx = (mt * 16 + lid) * 64 + ((ks * 16 + grp * 4) ^ (lid << 2));
      U8 a2h, a2l;
      a2h.v = *(const bf16x8*)&Shi[sidx];
      a2l.v = *(const bf16x8*)&Slo[sidx];
      ore[mt] = __builtin_amdgcn_mfma_f32_16x16x32_bf16(a2h.v, bvh.v, ore[mt], 0, 0, 0);
      ore[mt] = __builtin_amdgcn_mfma_f32_16x16x32_bf16(a2l.v, bvh.v, ore[mt], 0, 0, 0);
      ore[mt] = __builtin_amdgcn_mfma_f32_16x16x32_bf16(a2h.v, bvl.v, ore[mt], 0, 0, 0);
      oim[mt] = __builtin_amdgcn_mfma_f32_16x16x32_bf16(a2h.v, bvi.v, oim[mt], 0, 0, 0);
      oim[mt] = __builtin_amdgcn_mfma_f32_16x16x32_bf16(a2l.v, bvi.v, oim[mt], 0, 0, 0);
      oim[mt] = __builtin_amdgcn_mfma_f32_16x16x32_bf16(a2h.v, bvj.v, oim[mt], 0, 0, 0);
    }
  }
  __syncthreads();                      // before next tile's S overwrite
}

__global__ __launch_bounds__(256, 3) void attn_kernel(
    const uint2* __restrict__ qf, const uint2* __restrict__ kf,
    const uint2* __restrict__ vfT, float2* __restrict__ of) {
  __shared__ __align__(16) unsigned char smem[16896];
  unsigned* Shi = (unsigned*)smem;              // [32 x][64 y] dw, swizzled
  unsigned* Slo = (unsigned*)(smem + 8192);
  float* zred = (float*)(smem + 16384);         // [4 w][32 x]

  int tid = threadIdx.x;
  int w = tid >> 6;                             // wave 0..3
  int lane = tid & 63;
  int grp = lane >> 4;                          // k-group 0..3
  int lid = lane & 15;

  unsigned v0 = blockIdx.x;                     // 0..2175
  unsigned cc = v0 & 7u;                        // XCD
  unsigned jj = v0 >> 3;                        // 0..271
  int bh = (int)(cc + 8u * (jj / 17u));
  int x0 = (int)(jj % 17u) * 32;

  const uint2* qb = qf + (size_t)bh * (64 * 514);
  const uint2* kb = kf + (size_t)bh * (64 * 514);
  const uint2* vb = vfT + (size_t)bh * (514 * 64);

  // ---- A fragments (q) direct from global (coalesced per quarter) ----
  U8 Ah[2][4], Al[2][4];
#pragma unroll
  for (int mt = 0; mt < 2; ++mt) {
    int gx = x0 + mt * 16 + lid;
    bool qv = gx < 514;
#pragma unroll
    for (int ks = 0; ks < 4; ++ks)
#pragma unroll
      for (int jp = 0; jp < 4; ++jp) {
        int e = ks * 16 + grp * 4 + jp;
        uint2 d = make_uint2(0, 0);
        if (qv) d = qb[(size_t)e * 514 + gx];
        Ah[mt][ks].u[jp] = d.x;
        Al[mt][ks].u[jp] = d.y;
      }
  }

  float zacc[8] = {0.f, 0.f, 0.f, 0.f, 0.f, 0.f, 0.f, 0.f};
  f32x4 ore[2] = {{0.f, 0.f, 0.f, 0.f}, {0.f, 0.f, 0.f, 0.f}};
  f32x4 oim[2] = {{0.f, 0.f, 0.f, 0.f}, {0.f, 0.f, 0.f, 0.f}};

#pragma unroll 1
  for (int yt = 0; yt < 8; ++yt)
    attn_tile<false>(yt * 64, kb, vb, Ah, Al, Shi, Slo, zacc, ore, oim,
                     w, grp, lid);
  attn_tile<true>(512, kb, vb, Ah, Al, Shi, Slo, zacc, ore, oim,
                  w, grp, lid);

  // ---- Z reduction: per-lane partials -> per-x totals ----
#pragma unroll
  for (int mt = 0; mt < 2; ++mt)
#pragma unroll
    for (int r = 0; r < 4; ++r) {
      float z = zacc[mt * 4 + r];
      z += __shfl_xor(z, 1); z += __shfl_xor(z, 2);
      z += __shfl_xor(z, 4); z += __shfl_xor(z, 8);
      zacc[mt * 4 + r] = z;
    }
  if (lid == 0) {
#pragma unroll
    for (int mt = 0; mt < 2; ++mt)
#pragma unroll
      for (int r = 0; r < 4; ++r)
        zred[w * 32 + mt * 16 + grp * 4 + r] = zacc[mt * 4 + r];
  }
  __syncthreads();
  // ---- normalize + stage output tile [64 e][32 x] (swz x ^ ((e&7)<<2)) ----
  float2* ov = (float2*)smem;           // aliases S planes (16 KB)
#pragma unroll
  for (int mt = 0; mt < 2; ++mt)
#pragma unroll
    for (int r = 0; r < 4; ++r) {
      int x = mt * 16 + grp * 4 + r;
      float z = zred[x] + zred[32 + x] + zred[64 + x] + zred[96 + x];
      float inv = 1.f / fmaxf(z, 1e-12f);
      int e = w * 16 + lid;
      ov[e * 32 + (x ^ ((e & 7) << 2))] =
          make_float2(ore[mt][r] * inv, oim[mt][r] * inv);
    }
  __syncthreads();
  // ---- coalesced write: of[(bh*64+e)*513 + x] ----
  {
    float2* ob = of + (size_t)bh * 64 * 513;
#pragma unroll
    for (int i = 0; i < 4; ++i) {
      int e = (tid >> 4) + i * 16;
      int xq = (tid & 15) * 2;
      int sw = (e & 7) << 2;
      float2 a = ov[e * 32 + (xq ^ sw)];
      float2 b2 = ov[e * 32 + ((xq + 1) ^ sw)];
      int gx = x0 + xq;
      if (gx < 513) ob[(size_t)e * 513 + gx] = a;
      if (gx + 1 < 513) ob[(size_t)e * 513 + gx + 1] = b2;
    }
  }
}

// ------- Inverse rfft x2 (ortho): two Hermitian rows per complex IFFT ---
// rows r0=2*bid, r0+1 of `of` (stride 513); z = F0 + i*F1 (full spectrum
// via Hermitian mirror). CRITICAL: Im of bins 0 and 512 is ZEROED --
// irfft ignores them; leaving them contaminates the pair partner's output
// at ~|Im|/32 (the r9/r10 failure). Output rows adjacent -> float2 store.
__global__ __launch_bounds__(256) void fft_inv2_kernel(
    const float2* __restrict__ in, float* __restrict__ out) {
  __shared__ float2 sb0[1024];
  __shared__ float2 sb1[1024];
  __shared__ float2 twd[512];
  int tid = threadIdx.x;
  size_t r0 = (size_t)blockIdx.x * 2;   // even row
  const float2* ip0 = in + r0 * 513;
  const float2* ip1 = ip0 + 513;
#pragma unroll
  for (int i = 0; i < 4; ++i) {
    int idx = tid + i * 256;
    float2 z;
    if (idx < 513) {
      float2 u0 = ip0[idx], u1 = ip1[idx];
      if (idx == 0 || idx == 512) { u0.y = 0.f; u1.y = 0.f; }
      z = make_float2(u0.x - u1.y, u0.y + u1.x);
    } else {                            // conj mirror (m in [1,511])
      int m = 1024 - idx;
      float2 u0 = ip0[m], u1 = ip1[m];
      z = make_float2(u0.x + u1.y, u1.x - u0.y);
    }
    sb0[idx] = z;
  }
  for (int kk = tid; kk < 512; kk += 256) {
    float ang = 6.283185307179586f * (float)kk * (1.0f / 1024.0f);
    float sn, cs;
    __sincosf(ang, &sn, &cs);
    twd[kk] = make_float2(cs, sn);
  }
  fft1024(sb0, sb1, twd, tid);
  int e = (int)(r0 & 63);               // even
  int h = (int)((r0 >> 6) & 7);
  size_t b = r0 >> 9;
  float* op = out + b * (size_t)(1024 * 512) + (size_t)h * 64 + e;
  const float sc = 0.03125f;            // 1/sqrt(1024)
#pragma unroll
  for (int i = 0; i < 4; ++i) {
    int l = tid + i * 256;
    *(float2*)(op + (size_t)l * 512) =
        make_float2(sb0[l].x * sc, sb0[l].y * sc);
  }
}

// ---------------- launch ------------------------------------------------
extern "C" void kernel_launch(void* const* d_in, const int* in_sizes, int n_in,
                              void* d_out, int out_size, void* d_ws, size_t ws_size,
                              hipStream_t stream) {
  const float* q = (const float*)d_in[0];
  const float* k = (const float*)d_in[1];
  const float* v = (const float*)d_in[2];
  const float* W = (const float*)d_in[3];
  const float* bias = (const float*)d_in[4];
  float* out = (float*)d_out;

  // Workspace map (float offsets), regions of 8,421,376 floats each:
  //   A   [0)         reused: q2t -> kT -> vT -> vfT
  //   QFR [8421376)   reused: XPhi+XPlo (split q) -> qf (bf16-split freq)
  //   R2  [16842752)  reused: Wsp (split W) -> vf -> of
  //   R3  [25264128)  kf
  float* wsf = (float*)d_ws;
  float*    A    = wsf;
  uint2*    vfT  = (uint2*)wsf;
  unsigned* XPhi = (unsigned*)(wsf + 8421376);
  unsigned* XPlo = XPhi + (size_t)16 * 1024 * 256;   // +16 MB
  ushort4*  qf   = (ushort4*)(wsf + 8421376);
  uint2*    Wsp  = (uint2*)(wsf + 16842752);
  ushort4*  vf   = (ushort4*)(wsf + 16842752);
  float2*   of   = (float2*)(wsf + 16842752);        // overwrites vf
  ushort4*  kf   = (ushort4*)(wsf + 25264128);

  transpose_q_split<<<dim3(32, 16, 16), 256, 0, stream>>>(q, XPhi, XPlo);
  transpose_w_split<<<dim3(32, 32), 256, 0, stream>>>(W, Wsp);
  conv_glu_mfma<<<dim3(1024), 512, 0, stream>>>(XPhi, XPlo, Wsp, bias, A);
  fft_fwd2_kernel<<<dim3(4096), 256, 0, stream>>>(A, qf, 0.03125f * 0.125f);
  transpose_kernel<<<dim3(32, 16, 16), 256, 0, stream>>>(k, A);
  fft_fwd2_kernel<<<dim3(4096), 256, 0, stream>>>(A, kf, 0.03125f);
  transpose_kernel<<<dim3(32, 16, 16), 256, 0, stream>>>(v, A);
  fft_fwd2_kernel<<<dim3(4096), 256, 0, stream>>>(A, vf, 0.03125f);
  vft_kernel<<<dim3(9, 128), 256, 0, stream>>>((const uint2*)vf, vfT);
  attn_kernel<<<dim3(2176), 256, 0, stream>>>((const uint2*)qf, (const uint2*)kf,
                                              vfT, of);
  fft_inv2_kernel<<<dim3(4096), 256, 0, stream>>>(of, out);
}